// Round 8
// baseline (1120.665 us; speedup 1.0000x reference)
//
#include <hip/hip_runtime.h>
#include <stdint.h>

typedef __bf16 bf16;
typedef __attribute__((ext_vector_type(4))) float f32x4;
typedef __attribute__((ext_vector_type(8))) __bf16 bf16x8;
typedef __attribute__((ext_vector_type(4))) __bf16 bf16x4;
typedef __attribute__((ext_vector_type(4))) short s16x4;

#define DM   1024
#define NH   16
#define HDIM 64
#define BB   2
#define SEQ  2048
#define MR   (BB * SEQ)
#define DFF  4096
#define MEG  (1024 * 1024)

// ---------------- dtype detection: 1 = bf16, 0 = f32 ----------------
__global__ void detect_kernel(const unsigned int* __restrict__ xw,
                              int* __restrict__ flag) {
  int tid = threadIdx.x;
  int bad = 0;
  for (int i = tid; i < 4096; i += 64) {
    unsigned int w = xw[i];
    float flo = __uint_as_float((w & 0xffffu) << 16);
    if (!(fabsf(flo) < 100.f)) bad = 1;
  }
  unsigned long long m = __ballot(bad);
  if (tid == 0) *flag = (m == 0ull) ? 1 : 0;
}

// ---------------- input canonicalization -> bf16 ----------------
__global__ __launch_bounds__(256) void cvt_big_kernel(
    const void* __restrict__ src, bf16* __restrict__ dst, int n4,
    const int* __restrict__ flag) {
  int i = blockIdx.x * 256 + threadIdx.x;
  if (i >= n4) return;
  if (*flag) {
    ((bf16x4*)dst)[i] = ((const bf16x4*)src)[i];
  } else {
    float4 v = ((const float4*)src)[i];
    bf16x4 o = {(bf16)v.x, (bf16)v.y, (bf16)v.z, (bf16)v.w};
    ((bf16x4*)dst)[i] = o;
  }
}

struct P16 { const void* p[16]; };
__global__ __launch_bounds__(256) void cvt_small_kernel(
    P16 ps, bf16* __restrict__ dstbase, const int* __restrict__ flag) {
  const int ncnt[16] = {1024,1024,1024,1024,1024,1024,1024,1024,
                        4096,1024,1024,1024,1024,1024,1024,1024};
  const int doff[16] = {0,1024,2048,3072,4096,5120,6144,7168,
                        8192,12288,13312,14336,15360,16384,17408,18432};
  int b = blockIdx.x;
  int n = ncnt[b];
  bool isbf = (*flag) != 0;
  const void* s = ps.p[b];
  bf16* d = dstbase + doff[b];
  for (int i = threadIdx.x; i * 4 < n; i += 256) {
    if (isbf) {
      ((bf16x4*)d)[i] = ((const bf16x4*)s)[i];
    } else {
      float4 v = ((const float4*)s)[i];
      bf16x4 o = {(bf16)v.x, (bf16)v.y, (bf16)v.z, (bf16)v.w};
      ((bf16x4*)d)[i] = o;
    }
  }
}

// ---------------- async global->LDS, 16B per lane ----------------
static __device__ __forceinline__ void gl_lds16(const bf16* g, bf16* l) {
  auto gp = reinterpret_cast<__attribute__((address_space(1))) unsigned int*>(
      reinterpret_cast<uintptr_t>(g));
  auto lp = reinterpret_cast<__attribute__((address_space(3))) unsigned int*>(
      (unsigned int)reinterpret_cast<uintptr_t>(l));
  __builtin_amdgcn_global_load_lds(gp, lp, 16, 0, 0);
}

static __device__ __forceinline__ s16x4 as_s16x4(bf16x4 v) {
  s16x4 r;
  __builtin_memcpy(&r, &v, 8);
  return r;
}

// ---------------- batched weight transpose v2: 64x32 tiles, u32 loads,
// b128 stores. wt[n][k] = w[k][n]. ----------------------------------------
struct WTB {
  const void* src[10];
  int dstoff[10];
  int K[10], N[10];
  int bstart[10];
};
__global__ __launch_bounds__(256) void wt_all_kernel(WTB wb, bf16* __restrict__ wtbase,
                                                     const int* __restrict__ flag) {
  __shared__ alignas(16) bf16 tile[64][40];  // 80B rows: 16B-aligned
  int bid = blockIdx.x;
  int wi = 0;
  while (wi < 9 && bid >= wb.bstart[wi + 1]) ++wi;
  int rel = bid - wb.bstart[wi];
  int N = wb.N[wi], K = wb.K[wi];
  int nb = N >> 6;
  int n0 = (rel % nb) * 64, k0 = (rel / nb) * 32;
  const void* w = wb.src[wi];
  bf16* wt = wtbase + wb.dstoff[wi];
  bool isbf = (*flag) != 0;
  int tid = threadIdx.x;
  int np = tid & 31, tk = tid >> 5;  // np: n-pair 0..31, tk: k-row base 0..7
#pragma unroll
  for (int i = 0; i < 4; ++i) {
    int kl = tk + i * 8;
    bf16 b0, b1;
    if (isbf) {
      unsigned int u = *(const unsigned int*)(
          (const bf16*)w + (size_t)(k0 + kl) * N + n0 + np * 2);
      unsigned short s0 = (unsigned short)(u & 0xffffu);
      unsigned short s1 = (unsigned short)(u >> 16);
      __builtin_memcpy(&b0, &s0, 2);
      __builtin_memcpy(&b1, &s1, 2);
    } else {
      const float* fp = (const float*)w + (size_t)(k0 + kl) * N + n0 + np * 2;
      b0 = (bf16)fp[0];
      b1 = (bf16)fp[1];
    }
    tile[np * 2][kl] = b0;
    tile[np * 2 + 1][kl] = b1;
  }
  __syncthreads();
  int nl = tid >> 2, kq = tid & 3;  // nl 0..63, kq*8: k-octet
  bf16x8 v = *(const bf16x8*)(&tile[nl][kq * 8]);
  *(bf16x8*)(wt + (size_t)(n0 + nl) * K + k0 + kq * 8) = v;
}

// ---------------- GEMM v2: BK=64 (2 sub-steps per barrier pair -> half the
// vmcnt(0)-drain stalls), flat grid + XCD swizzle, C = A @ Bt^T + bias -----
template <int TM>
__global__ __launch_bounds__(256) void gemm_kernel(
    const bf16* __restrict__ A, const bf16* __restrict__ Bt,
    const bf16* __restrict__ bias, bf16* __restrict__ outb,
    int M, int N, int K, int relu, int nbx) {
  constexpr int NI = TM / 32;
  constexpr int WM = TM / 2;
  constexpr int CA = TM / 64;
  __shared__ alignas(16) bf16 As[2][TM * 32];
  __shared__ alignas(16) bf16 Bs[2][128 * 32];
  int tid = threadIdx.x;
  int lane = tid & 63, wv = tid >> 6;
  int quad = lane >> 4, l15 = lane & 15;
  int wg = blockIdx.x;
  int w = (wg & 7) * (gridDim.x >> 3) + (wg >> 3);  // XCD-contiguous
  int bx = w % nbx, by = w / nbx;
  int m0 = by * TM, n0 = bx * 128;
  int wm = wv >> 1, wn = wv & 1;

  f32x4 acc[NI][4];
#pragma unroll
  for (int i = 0; i < NI; ++i)
#pragma unroll
    for (int j = 0; j < 4; ++j) acc[i][j] = (f32x4){0.f, 0.f, 0.f, 0.f};

  int sr = lane >> 2, sc = (lane & 3) * 8;
  const bf16* gA[CA];
  bf16* lA0[CA];
  bf16* lA1[CA];
#pragma unroll
  for (int t = 0; t < CA; ++t) {
    int ch = wv * CA + t;
    gA[t] = A + (size_t)(m0 + ch * 16 + sr) * K + sc;
    lA0[t] = As[0] + ch * 512 + lane * 8;
    lA1[t] = As[1] + ch * 512 + lane * 8;
  }
  const bf16* gB0 = Bt + (size_t)(n0 + (wv * 2) * 16 + sr) * K + sc;
  const bf16* gB1 = Bt + (size_t)(n0 + (wv * 2 + 1) * 16 + sr) * K + sc;
  bf16* lB00 = Bs[0] + (wv * 2) * 512 + lane * 8;
  bf16* lB01 = Bs[1] + (wv * 2) * 512 + lane * 8;
  bf16* lB10 = Bs[0] + (wv * 2 + 1) * 512 + lane * 8;
  bf16* lB11 = Bs[1] + (wv * 2 + 1) * 512 + lane * 8;

  for (int k0 = 0; k0 < K; k0 += 64) {
#pragma unroll
    for (int t = 0; t < CA; ++t) {
      gl_lds16(gA[t] + k0, lA0[t]);
      gl_lds16(gA[t] + k0 + 32, lA1[t]);
    }
    gl_lds16(gB0 + k0, lB00);
    gl_lds16(gB0 + k0 + 32, lB01);
    gl_lds16(gB1 + k0, lB10);
    gl_lds16(gB1 + k0 + 32, lB11);
    __syncthreads();
#pragma unroll
    for (int s = 0; s < 2; ++s) {
      bf16x8 af[NI], bfr[4];
#pragma unroll
      for (int i = 0; i < NI; ++i)
        af[i] = *(const bf16x8*)(As[s] + (wm * WM + i * 16 + l15) * 32 + quad * 8);
#pragma unroll
      for (int j = 0; j < 4; ++j)
        bfr[j] = *(const bf16x8*)(Bs[s] + (wn * 64 + j * 16 + l15) * 32 + quad * 8);
#pragma unroll
      for (int i = 0; i < NI; ++i)
#pragma unroll
        for (int j = 0; j < 4; ++j)
          acc[i][j] = __builtin_amdgcn_mfma_f32_16x16x32_bf16(af[i], bfr[j],
                                                              acc[i][j], 0, 0, 0);
    }
    __syncthreads();
  }

#pragma unroll
  for (int j = 0; j < 4; ++j) {
    int col = n0 + wn * 64 + j * 16 + l15;
    float bval = (float)bias[col];
#pragma unroll
    for (int i = 0; i < NI; ++i) {
      int rb = m0 + wm * WM + i * 16 + quad * 4;
#pragma unroll
      for (int r = 0; r < 4; ++r) {
        float v = acc[i][j][r] + bval;
        if (relu) v = fmaxf(v, 0.f);
        outb[(size_t)(rb + r) * N + col] = (bf16)v;
      }
    }
  }
}

// ---------------- split-K GEMM v2: BK=64, flat grid + XCD swizzle --------
__global__ __launch_bounds__(256) void gemm_splitk_kernel(
    const bf16* __restrict__ A, const bf16* __restrict__ Bt,
    float* __restrict__ pout, int M, int N, int KC, int Ktot, int nbx) {
  __shared__ alignas(16) bf16 As[2][128 * 32];
  __shared__ alignas(16) bf16 Bs[2][128 * 32];
  int tid = threadIdx.x;
  int lane = tid & 63, wv = tid >> 6;
  int quad = lane >> 4, l15 = lane & 15;
  int wg = blockIdx.x;
  int w = (wg & 7) * (gridDim.x >> 3) + (wg >> 3);  // XCD-contiguous
  int nxy = nbx * (M >> 7);
  int bz = w / nxy;
  int rem = w - bz * nxy;
  int bx = rem % nbx, by = rem / nbx;
  int m0 = by * 128, n0 = bx * 128;
  int wm = wv >> 1, wn = wv & 1;
  int kb = bz * KC;
  pout += (size_t)bz * M * N;

  f32x4 acc[4][4];
#pragma unroll
  for (int i = 0; i < 4; ++i)
#pragma unroll
    for (int j = 0; j < 4; ++j) acc[i][j] = (f32x4){0.f, 0.f, 0.f, 0.f};

  int sr = lane >> 2, sc = (lane & 3) * 8;
  const bf16* gA0 = A + (size_t)(m0 + (wv * 2) * 16 + sr) * Ktot + sc;
  const bf16* gA1 = A + (size_t)(m0 + (wv * 2 + 1) * 16 + sr) * Ktot + sc;
  const bf16* gB0 = Bt + (size_t)(n0 + (wv * 2) * 16 + sr) * Ktot + sc;
  const bf16* gB1 = Bt + (size_t)(n0 + (wv * 2 + 1) * 16 + sr) * Ktot + sc;
  bf16* lA00 = As[0] + (wv * 2) * 512 + lane * 8;
  bf16* lA01 = As[1] + (wv * 2) * 512 + lane * 8;
  bf16* lA10 = As[0] + (wv * 2 + 1) * 512 + lane * 8;
  bf16* lA11 = As[1] + (wv * 2 + 1) * 512 + lane * 8;
  bf16* lB00 = Bs[0] + (wv * 2) * 512 + lane * 8;
  bf16* lB01 = Bs[1] + (wv * 2) * 512 + lane * 8;
  bf16* lB10 = Bs[0] + (wv * 2 + 1) * 512 + lane * 8;
  bf16* lB11 = Bs[1] + (wv * 2 + 1) * 512 + lane * 8;

  for (int k0 = kb; k0 < kb + KC; k0 += 64) {
    gl_lds16(gA0 + k0, lA00);
    gl_lds16(gA0 + k0 + 32, lA01);
    gl_lds16(gA1 + k0, lA10);
    gl_lds16(gA1 + k0 + 32, lA11);
    gl_lds16(gB0 + k0, lB00);
    gl_lds16(gB0 + k0 + 32, lB01);
    gl_lds16(gB1 + k0, lB10);
    gl_lds16(gB1 + k0 + 32, lB11);
    __syncthreads();
#pragma unroll
    for (int s = 0; s < 2; ++s) {
      bf16x8 af[4], bfr[4];
#pragma unroll
      for (int i = 0; i < 4; ++i)
        af[i] = *(const bf16x8*)(As[s] + (wm * 64 + i * 16 + l15) * 32 + quad * 8);
#pragma unroll
      for (int j = 0; j < 4; ++j)
        bfr[j] = *(const bf16x8*)(Bs[s] + (wn * 64 + j * 16 + l15) * 32 + quad * 8);
#pragma unroll
      for (int i = 0; i < 4; ++i)
#pragma unroll
        for (int j = 0; j < 4; ++j)
          acc[i][j] = __builtin_amdgcn_mfma_f32_16x16x32_bf16(af[i], bfr[j],
                                                              acc[i][j], 0, 0, 0);
    }
    __syncthreads();
  }
#pragma unroll
  for (int j = 0; j < 4; ++j) {
    int col = n0 + wn * 64 + j * 16 + l15;
#pragma unroll
    for (int i = 0; i < 4; ++i) {
      int rb = m0 + wm * 64 + i * 16 + quad * 4;
#pragma unroll
      for (int r = 0; r < 4; ++r)
        pout[(size_t)(rb + r) * N + col] = acc[i][j][r];
    }
  }
}

// ---------------- V pre-transpose: [b][kv][h*64+d] -> [b*NH+h][d][skv] ----
__global__ __launch_bounds__(256) void vt_pre_kernel(
    const bf16* __restrict__ v, int vstride, bf16* __restrict__ vt, int skv) {
  __shared__ bf16 tile[32][33];
  int tid = threadIdx.x;
  int tx = tid & 31, ty = tid >> 5;
  int kv0 = blockIdx.x * 32, d0 = blockIdx.y * 32;
  int bh = blockIdx.z;
  int b = bh >> 4, h = bh & 15;
  const bf16* src = v + (size_t)b * skv * vstride + h * HDIM;
#pragma unroll
  for (int i = 0; i < 4; ++i)
    tile[ty + i * 8][tx] = src[(size_t)(kv0 + ty + i * 8) * vstride + d0 + tx];
  __syncthreads();
  bf16* dst = vt + ((size_t)bh * HDIM + d0) * skv + kv0;
#pragma unroll
  for (int i = 0; i < 4; ++i)
    dst[(size_t)(ty + i * 8) * skv + tx] = tile[tx][ty + i * 8];
}

// ---------------- flash v11: flash9 structure at 8 blocks/CU ---------------
// Single-buffered K/V (16KB LDS) + nsplit=4 (grid 2048 = 8 blocks/CU x 4
// waves = 32 waves/CU). In-block load/compute overlap is given up (2
// barriers/chunk); 8 independent blocks per CU time-share all stalls.
// VGPR=64 = exactly the 8-wave/SIMD budget.
__global__ __launch_bounds__(256, 8) void flash11_kernel(
    const bf16* __restrict__ Q, int qstride,
    const bf16* __restrict__ Kk, int kstride,
    const bf16* __restrict__ VT, bf16* __restrict__ ctx,
    float* __restrict__ opart, float* __restrict__ lpart,
    int skv, int causal, int nsplit) {
  __shared__ alignas(16) bf16 KTl[64 * 64];
  __shared__ alignas(16) bf16 VTl[64 * 64];
  int tid = threadIdx.x;
  int lane = tid & 63, wv = tid >> 6, quad = lane >> 4, l15 = lane & 15;
  int wg = blockIdx.x;
  int cpx = gridDim.x >> 3;
  int w = (wg & 7) * cpx + (wg >> 3);  // XCD-contiguous work id
  int qb = w & 15;
  int h = (w >> 4) & 15;
  int zz = w >> 8;
  int b = zz / nsplit;
  int half = zz - b * nsplit;
  int q0 = qb * 128;
  int qw = q0 + wv * 32;
  int l7 = l15 & 7;

  // Q as B-operand of QK^T; fold 0.125*log2(e) so softmax is pure v_exp
  bf16x8 qf[2][2];
  const float qsc = 0.125f * 1.44269504f;
#pragma unroll
  for (int a = 0; a < 2; ++a) {
    const bf16* qp = Q + (size_t)(b * SEQ + qw + a * 16 + l15) * qstride + h * HDIM;
    qf[a][0] = *(const bf16x8*)(qp + quad * 8);
    qf[a][1] = *(const bf16x8*)(qp + 32 + quad * 8);
#pragma unroll
    for (int j = 0; j < 8; ++j) {
      qf[a][0][j] = (bf16)((float)qf[a][0][j] * qsc);
      qf[a][1][j] = (bf16)((float)qf[a][1][j] * qsc);
    }
  }
  s16x4 onesA = {0x3F80, 0x3F80, 0x3F80, 0x3F80};  // bf16 1.0 x4

  // o^T accumulators: o[a][jt] rows = d-local (quad*4+r), col = q (l15)
  f32x4 o[2][4], oL[2];
#pragma unroll
  for (int a = 0; a < 2; ++a) {
    oL[a] = (f32x4){0.f, 0.f, 0.f, 0.f};
#pragma unroll
    for (int j = 0; j < 4; ++j) o[a][j] = (f32x4){0.f, 0.f, 0.f, 0.f};
  }

  int nch_tot = causal ? (q0 + 128) / 64 : skv / 64;
  int c_lo = (half * nch_tot) / nsplit;
  int c_hi = ((half + 1) * nch_tot) / nsplit;

  // staging geometry: wave wv owns tile rows [wv*16, wv*16+16), two 8-row
  // gl_lds ops each. Global source col-segment pre-swizzled so that the
  // LINEAR lds write lands data at physical slot (colseg ^ (row&7)).
  int l8 = lane >> 3;
  int colseg = (lane & 7) ^ l8;  // (row&7)==l8 for both ops (row0%8==0)
  int grow = wv * 16 + l8;
  const bf16* kbase = Kk + ((size_t)b * skv + grow) * kstride + h * HDIM + colseg * 8;
  const bf16* vbase = VT + ((size_t)(b * NH + h) * HDIM + grow) * skv + colseg * 8;
  bf16* kls = &KTl[wv * 1024];  // lane-uniform dest base (lane0 value)
  bf16* vls = &VTl[wv * 1024];

  auto STAGE = [&](int cc) {
    const bf16* ks = kbase + (size_t)(cc * 64) * kstride;
    const bf16* vs = vbase + cc * 64;
    gl_lds16(ks, kls);
    gl_lds16(ks + (size_t)8 * kstride, kls + 512);
    gl_lds16(vs, vls);
    gl_lds16(vs + (size_t)8 * skv, vls + 512);
  };

  for (int c = c_lo; c < c_hi; ++c) {
    int kv0 = c * 64;
    __syncthreads();  // WAR: all waves' reads of previous chunk complete
    STAGE(c);
    __syncthreads();  // RAW: barrier drains vmcnt -> K/V staged & visible

    if (!causal || kv0 <= qw + 31) {  // wave-uniform skip of masked chunks
      bf16x4 p[2][4];
      // S^T = K @ Q^T per 16-row kv tile t; convert to bf16 in-register
#pragma unroll
      for (int t = 0; t < 4; ++t) {
        const bf16* kb = KTl + (t * 16 + l15) * 64;
        bf16x8 kt0 = *(const bf16x8*)(kb + ((quad ^ l7) << 3));
        bf16x8 kt1 = *(const bf16x8*)(kb + (((quad + 4) ^ l7) << 3));
#pragma unroll
        for (int a = 0; a < 2; ++a) {
          f32x4 z = (f32x4){0.f, 0.f, 0.f, 0.f};
          z = __builtin_amdgcn_mfma_f32_16x16x32_bf16(kt0, qf[a][0], z, 0, 0, 0);
          z = __builtin_amdgcn_mfma_f32_16x16x32_bf16(kt1, qf[a][1], z, 0, 0, 0);
          if (causal && kv0 + 63 > qw) {  // diagonal region: element mask
#pragma unroll
            for (int r = 0; r < 4; ++r)
              if (kv0 + t * 16 + quad * 4 + r > qw + a * 16 + l15)
                z[r] = -1e30f;
          }
          bf16x4 pk;
#pragma unroll
          for (int r = 0; r < 4; ++r) pk[r] = (bf16)exp2f(z[r]);
          p[a][t] = pk;
          // row-sum via ones-A MFMA: every lane gets l[q=l15] in all rows
          oL[a] = __builtin_amdgcn_mfma_f32_16x16x16bf16_1k(
              onesA, as_s16x4(pk), oL[a], 0, 0, 0);
        }
      }
      // PV: o^T[d][q] += V^T-frag (A) x P^T-D-frag (B), 16x16x16
#pragma unroll
      for (int jt = 0; jt < 4; ++jt) {
        const bf16* vb = VTl + (jt * 16 + l15) * 64;
        bf16x4 af[4];
#pragma unroll
        for (int t = 0; t < 4; ++t)
          af[t] = *(const bf16x4*)(
              vb + ((((t * 2 + (quad >> 1)) ^ l7) << 3) + ((quad & 1) << 2)));
#pragma unroll
        for (int a = 0; a < 2; ++a)
#pragma unroll
          for (int t = 0; t < 4; ++t)
            o[a][jt] = __builtin_amdgcn_mfma_f32_16x16x16bf16_1k(
                as_s16x4(af[t]), as_s16x4(p[a][t]), o[a][jt], 0, 0, 0);
      }
    }
  }

  if (nsplit == 1) {
#pragma unroll
    for (int a = 0; a < 2; ++a) {
      float inv = 1.0f / fmaxf(oL[a][0], 1e-30f);
      bf16* cp = ctx + (size_t)(b * SEQ + qw + a * 16 + l15) * DM + h * HDIM + quad * 4;
#pragma unroll
      for (int jt = 0; jt < 4; ++jt) {
        bf16x4 ob = {(bf16)(o[a][jt][0] * inv), (bf16)(o[a][jt][1] * inv),
                     (bf16)(o[a][jt][2] * inv), (bf16)(o[a][jt][3] * inv)};
        *(bf16x4*)(cp + jt * 16) = ob;
      }
    }
  } else {
    // additive partials: fixed-shift softmax means o/l just sum across splits
#pragma unroll
    for (int a = 0; a < 2; ++a) {
      float* op = opart + (size_t)half * MR * DM +
                  (size_t)(b * SEQ + qw + a * 16 + l15) * DM + h * HDIM + quad * 4;
#pragma unroll
      for (int jt = 0; jt < 4; ++jt) *(f32x4*)(op + jt * 16) = o[a][jt];
      if (lane < 16)
        lpart[(size_t)((half * BB + b) * NH + h) * SEQ + qw + a * 16 + l15] =
            oL[a][0];
    }
  }
}

// ---------------- kv-split combine: ctx = sum(o_s) / sum(l_s) -------------
template <int NS>
__global__ __launch_bounds__(256) void flash_comb_kernel(
    const float* __restrict__ opart, const float* __restrict__ lpart,
    bf16* __restrict__ ctx) {
  int row = blockIdx.x, tid = threadIdx.x;
  int b = row >> 11, q = row & (SEQ - 1);
  int h = tid >> 4;
  float l = 0.f;
#pragma unroll
  for (int s = 0; s < NS; ++s)
    l += lpart[(size_t)((s * BB + b) * NH + h) * SEQ + q];
  float inv = 1.0f / fmaxf(l, 1e-30f);
  float a0 = 0.f, a1 = 0.f, a2 = 0.f, a3 = 0.f;
#pragma unroll
  for (int s = 0; s < NS; ++s) {
    f32x4 v = ((const f32x4*)(opart + (size_t)s * MR * DM + (size_t)row * DM))[tid];
    a0 += v[0]; a1 += v[1]; a2 += v[2]; a3 += v[3];
  }
  bf16x4 ob = {(bf16)(a0 * inv), (bf16)(a1 * inv),
               (bf16)(a2 * inv), (bf16)(a3 * inv)};
  ((bf16x4*)(ctx + (size_t)row * DM))[tid] = ob;
}

// ---------------- fused split-K reduce + bias + residual + LayerNorm ------
template <int NP>
__global__ __launch_bounds__(256) void addnorm_red_kernel(
    const bf16* __restrict__ res, const float* __restrict__ part,
    const bf16* __restrict__ bias, const bf16* __restrict__ g,
    const bf16* __restrict__ be, bf16* __restrict__ yb,
    void* __restrict__ outAny, const int* __restrict__ flag) {
  int row = blockIdx.x, tid = threadIdx.x;
  float a0 = 0.f, a1 = 0.f, a2 = 0.f, a3 = 0.f;
#pragma unroll
  for (int p = 0; p < NP; ++p) {
    float4 v = ((const float4*)(part + (size_t)p * MR * DM + (size_t)row * DM))[tid];
    a0 += v.x; a1 += v.y; a2 += v.z; a3 += v.w;
  }
  bf16x4 bb = ((const bf16x4*)bias)[tid];
  bf16x4 rr = ((const bf16x4*)(res + (size_t)row * DM))[tid];
  float s0 = (float)rr[0] + a0 + (float)bb[0];
  float s1 = (float)rr[1] + a1 + (float)bb[1];
  float s2 = (float)rr[2] + a2 + (float)bb[2];
  float s3 = (float)rr[3] + a3 + (float)bb[3];
  float sum = s0 + s1 + s2 + s3;
  float sq = s0 * s0 + s1 * s1 + s2 * s2 + s3 * s3;
#pragma unroll
  for (int mk = 32; mk >= 1; mk >>= 1) {
    sum += __shfl_xor(sum, mk, 64);
    sq += __shfl_xor(sq, mk, 64);
  }
  __shared__ float red[8];
  int wvi = tid >> 6, lane = tid & 63;
  if (lane == 0) { red[wvi * 2] = sum; red[wvi * 2 + 1] = sq; }
  __syncthreads();
  sum = red[0] + red[2] + red[4] + red[6];
  sq = red[1] + red[3] + red[5] + red[7];
  float mu = sum * (1.0f / DM);
  float var = sq * (1.0f / DM) - mu * mu;
  float rstd = rsqrtf(var + 1e-5f);
  bf16x4 g4 = ((const bf16x4*)g)[tid];
  bf16x4 b4 = ((const bf16x4*)be)[tid];
  float y0 = (s0 - mu) * rstd * (float)g4[0] + (float)b4[0];
  float y1 = (s1 - mu) * rstd * (float)g4[1] + (float)b4[1];
  float y2 = (s2 - mu) * rstd * (float)g4[2] + (float)b4[2];
  float y3 = (s3 - mu) * rstd * (float)g4[3] + (float)b4[3];
  if (yb) {
    bf16x4 ob = {(bf16)y0, (bf16)y1, (bf16)y2, (bf16)y3};
    ((bf16x4*)(yb + (size_t)row * DM))[tid] = ob;
  }
  if (outAny) {
    if (*flag) {
      bf16x4 ob = {(bf16)y0, (bf16)y1, (bf16)y2, (bf16)y3};
      ((bf16x4*)outAny)[(size_t)row * 256 + tid] = ob;
    } else {
      ((float4*)outAny)[(size_t)row * 256 + tid] = make_float4(y0, y1, y2, y3);
    }
  }
}

extern "C" void kernel_launch(void* const* d_in, const int* in_sizes, int n_in,
                              void* d_out, int out_size, void* d_ws, size_t ws_size,
                              hipStream_t stream) {
  (void)in_sizes; (void)n_in; (void)out_size; (void)ws_size;
  const void* x_raw   = d_in[0];
  const void* enc_raw = d_in[1];

  char* ws = (char*)d_ws;
  size_t off = 0;
  auto alloc = [&](size_t bytes) -> void* {
    void* p = ws + off;
    off += (bytes + 255) & ~(size_t)255;
    return p;
  };
  const size_t SB = (size_t)MR * DM;
  int* flag    = (int*)alloc(256);
  bf16* smallb = (bf16*)alloc(20480 * 2);
  bf16* wt   = (bf16*)alloc((size_t)16 * MEG * 2);
  bf16* xb   = (bf16*)alloc(SB * 2);
  bf16* encb = (bf16*)alloc(SB * 2);
  bf16* vtg  = (bf16*)alloc(SB * 2);
  bf16* ctx  = (bf16*)alloc(SB * 2);
  bf16* hb1  = (bf16*)alloc(SB * 2);
  bf16* hb2  = (bf16*)alloc(SB * 2);
  bf16* qkv  = (bf16*)alloc(SB * 3 * 2);
  bf16* kvc  = (bf16*)alloc(SB * 2 * 2);
  float* part = (float*)alloc(SB * 4 * 4);
  float* lpart = (float*)alloc((size_t)4 * BB * NH * SEQ * 4);
  bf16* gbuf = qkv;
  bf16* qc   = xb;

  bf16* b_qkvs = smallb + 0;     bf16* b_os  = smallb + 3072;
  bf16* b_qc   = smallb + 4096;  bf16* b_kvc = smallb + 5120;
  bf16* b_oc   = smallb + 7168;  bf16* b_f1  = smallb + 8192;
  bf16* b_f2   = smallb + 12288;
  bf16* l1g = smallb + 13312; bf16* l1b = smallb + 14336;
  bf16* l2g = smallb + 15360; bf16* l2b = smallb + 16384;
  bf16* l3g = smallb + 17408; bf16* l3b = smallb + 18432;

  detect_kernel<<<1, 64, 0, stream>>>((const unsigned int*)x_raw, flag);
  cvt_big_kernel<<<(int)(SB / 1024), 256, 0, stream>>>(x_raw, xb, (int)(SB / 4), flag);
  cvt_big_kernel<<<(int)(SB / 1024), 256, 0, stream>>>(enc_raw, encb, (int)(SB / 4), flag);
  P16 ps;
  ps.p[0] = d_in[5];  ps.p[1] = d_in[7];  ps.p[2] = d_in[9];  ps.p[3] = d_in[11];
  ps.p[4] = d_in[13]; ps.p[5] = d_in[15]; ps.p[6] = d_in[17]; ps.p[7] = d_in[19];
  ps.p[8] = d_in[21]; ps.p[9] = d_in[23];
  ps.p[10] = d_in[24]; ps.p[11] = d_in[25]; ps.p[12] = d_in[26];
  ps.p[13] = d_in[27]; ps.p[14] = d_in[28]; ps.p[15] = d_in[29];
  cvt_small_kernel<<<16, 256, 0, stream>>>(ps, smallb, flag);

  WTB wb;
  const int wsrc[10] = {4, 6, 8, 10, 12, 14, 16, 18, 20, 22};
  for (int i = 0; i < 10; ++i) {
    wb.src[i] = d_in[wsrc[i]];
    wb.K[i] = 1024; wb.N[i] = 1024;
    wb.dstoff[i] = i * MEG;
  }
  wb.N[8] = 4096;
  wb.K[9] = 4096; wb.dstoff[9] = 12 * MEG;
  int bacc = 0;
  for (int i = 0; i < 10; ++i) {
    wb.bstart[i] = bacc;
    bacc += (wb.N[i] / 64) * (wb.K[i] / 32);
  }
  wt_all_kernel<<<bacc, 256, 0, stream>>>(wb, wt, flag);

  // ---- self attention (causal, kv-split x4 + additive combine) ----
  gemm_kernel<128><<<24 * 32, 256, 0, stream>>>(xb, wt, b_qkvs, qkv,
                                                MR, 3072, DM, 0, 24);
  vt_pre_kernel<<<dim3(SEQ / 32, 2, 32), 256, 0, stream>>>(qkv + 2048, 3072, vtg, SEQ);
  flash11_kernel<<<16 * 16 * BB * 4, 256, 0, stream>>>(
      qkv, 3072, qkv + 1024, 3072, vtg, ctx, part, lpart, SEQ, 1, 4);
  flash_comb_kernel<4><<<MR, 256, 0, stream>>>(part, lpart, ctx);
  gemm_splitk_kernel<<<8 * 32 * 2, 256, 0, stream>>>(
      ctx, wt + (size_t)3 * MEG, part, MR, DM, 512, DM, 8);
  addnorm_red_kernel<2><<<MR, 256, 0, stream>>>(xb, part, b_os, l1g, l1b,
                                                hb1, nullptr, flag);
  // ---- cross attention (kv-split x4 + additive combine) ----
  gemm_kernel<64><<<8 * 64, 256, 0, stream>>>(hb1, wt + (size_t)4 * MEG,
                                              b_qc, qc, MR, DM, DM, 0, 8);
  gemm_kernel<128><<<16 * 32, 256, 0, stream>>>(encb, wt + (size_t)5 * MEG,
                                                b_kvc, kvc, MR, 2048, DM, 0, 16);
  vt_pre_kernel<<<dim3(SEQ / 32, 2, 32), 256, 0, stream>>>(kvc + 1024, 2048, vtg, SEQ);
  flash11_kernel<<<16 * 16 * BB * 4, 256, 0, stream>>>(
      qc, 1024, kvc, 2048, vtg, ctx, part, lpart, SEQ, 0, 4);
  flash_comb_kernel<4><<<MR, 256, 0, stream>>>(part, lpart, ctx);
  gemm_splitk_kernel<<<8 * 32 * 2, 256, 0, stream>>>(
      ctx, wt + (size_t)7 * MEG, part, MR, DM, 512, DM, 8);
  addnorm_red_kernel<2><<<MR, 256, 0, stream>>>(hb1, part, b_oc, l2g, l2b,
                                                hb2, nullptr, flag);
  // ---- FFN ----
  gemm_kernel<128><<<32 * 32, 256, 0, stream>>>(hb2, wt + (size_t)8 * MEG,
                                                b_f1, gbuf, MR, DFF, DM, 1, 32);
  gemm_splitk_kernel<<<8 * 32 * 4, 256, 0, stream>>>(
      gbuf, wt + (size_t)12 * MEG, part, MR, DM, 1024, DFF, 8);
  addnorm_red_kernel<4><<<MR, 256, 0, stream>>>(hb2, part, b_f2, l3g, l3b,
                                                nullptr, d_out, flag);
}

// Round 9
// 865.905 us; speedup vs baseline: 1.2942x; 1.2942x over previous
//
#include <hip/hip_runtime.h>
#include <stdint.h>

typedef __bf16 bf16;
typedef __attribute__((ext_vector_type(4))) float f32x4;
typedef __attribute__((ext_vector_type(8))) __bf16 bf16x8;
typedef __attribute__((ext_vector_type(4))) __bf16 bf16x4;
typedef __attribute__((ext_vector_type(4))) short s16x4;

#define DM   1024
#define NH   16
#define HDIM 64
#define BB   2
#define SEQ  2048
#define MR   (BB * SEQ)
#define DFF  4096
#define MEG  (1024 * 1024)

// ---------------- dtype detection: 1 = bf16, 0 = f32 ----------------
__global__ void detect_kernel(const unsigned int* __restrict__ xw,
                              int* __restrict__ flag) {
  int tid = threadIdx.x;
  int bad = 0;
  for (int i = tid; i < 4096; i += 64) {
    unsigned int w = xw[i];
    float flo = __uint_as_float((w & 0xffffu) << 16);
    if (!(fabsf(flo) < 100.f)) bad = 1;
  }
  unsigned long long m = __ballot(bad);
  if (tid == 0) *flag = (m == 0ull) ? 1 : 0;
}

// ---------------- input canonicalization -> bf16 ----------------
__global__ __launch_bounds__(256) void cvt_big_kernel(
    const void* __restrict__ src, bf16* __restrict__ dst, int n4,
    const int* __restrict__ flag) {
  int i = blockIdx.x * 256 + threadIdx.x;
  if (i >= n4) return;
  if (*flag) {
    ((bf16x4*)dst)[i] = ((const bf16x4*)src)[i];
  } else {
    float4 v = ((const float4*)src)[i];
    bf16x4 o = {(bf16)v.x, (bf16)v.y, (bf16)v.z, (bf16)v.w};
    ((bf16x4*)dst)[i] = o;
  }
}

struct P16 { const void* p[16]; };
__global__ __launch_bounds__(256) void cvt_small_kernel(
    P16 ps, bf16* __restrict__ dstbase, const int* __restrict__ flag) {
  const int ncnt[16] = {1024,1024,1024,1024,1024,1024,1024,1024,
                        4096,1024,1024,1024,1024,1024,1024,1024};
  const int doff[16] = {0,1024,2048,3072,4096,5120,6144,7168,
                        8192,12288,13312,14336,15360,16384,17408,18432};
  int b = blockIdx.x;
  int n = ncnt[b];
  bool isbf = (*flag) != 0;
  const void* s = ps.p[b];
  bf16* d = dstbase + doff[b];
  for (int i = threadIdx.x; i * 4 < n; i += 256) {
    if (isbf) {
      ((bf16x4*)d)[i] = ((const bf16x4*)s)[i];
    } else {
      float4 v = ((const float4*)s)[i];
      bf16x4 o = {(bf16)v.x, (bf16)v.y, (bf16)v.z, (bf16)v.w};
      ((bf16x4*)d)[i] = o;
    }
  }
}

// ---------------- async global->LDS, 16B per lane ----------------
static __device__ __forceinline__ void gl_lds16(const bf16* g, bf16* l) {
  auto gp = reinterpret_cast<__attribute__((address_space(1))) unsigned int*>(
      reinterpret_cast<uintptr_t>(g));
  auto lp = reinterpret_cast<__attribute__((address_space(3))) unsigned int*>(
      (unsigned int)reinterpret_cast<uintptr_t>(l));
  __builtin_amdgcn_global_load_lds(gp, lp, 16, 0, 0);
}

static __device__ __forceinline__ s16x4 as_s16x4(bf16x4 v) {
  s16x4 r;
  __builtin_memcpy(&r, &v, 8);
  return r;
}

// ---------------- batched weight transpose v2: 64x32 tiles, u32 loads,
// b128 stores. wt[n][k] = w[k][n]. ----------------------------------------
struct WTB {
  const void* src[10];
  int dstoff[10];
  int K[10], N[10];
  int bstart[10];
};
__global__ __launch_bounds__(256) void wt_all_kernel(WTB wb, bf16* __restrict__ wtbase,
                                                     const int* __restrict__ flag) {
  __shared__ alignas(16) bf16 tile[64][40];  // 80B rows: 16B-aligned
  int bid = blockIdx.x;
  int wi = 0;
  while (wi < 9 && bid >= wb.bstart[wi + 1]) ++wi;
  int rel = bid - wb.bstart[wi];
  int N = wb.N[wi], K = wb.K[wi];
  int nb = N >> 6;
  int n0 = (rel % nb) * 64, k0 = (rel / nb) * 32;
  const void* w = wb.src[wi];
  bf16* wt = wtbase + wb.dstoff[wi];
  bool isbf = (*flag) != 0;
  int tid = threadIdx.x;
  int np = tid & 31, tk = tid >> 5;  // np: n-pair 0..31, tk: k-row base 0..7
#pragma unroll
  for (int i = 0; i < 4; ++i) {
    int kl = tk + i * 8;
    bf16 b0, b1;
    if (isbf) {
      unsigned int u = *(const unsigned int*)(
          (const bf16*)w + (size_t)(k0 + kl) * N + n0 + np * 2);
      unsigned short s0 = (unsigned short)(u & 0xffffu);
      unsigned short s1 = (unsigned short)(u >> 16);
      __builtin_memcpy(&b0, &s0, 2);
      __builtin_memcpy(&b1, &s1, 2);
    } else {
      const float* fp = (const float*)w + (size_t)(k0 + kl) * N + n0 + np * 2;
      b0 = (bf16)fp[0];
      b1 = (bf16)fp[1];
    }
    tile[np * 2][kl] = b0;
    tile[np * 2 + 1][kl] = b1;
  }
  __syncthreads();
  int nl = tid >> 2, kq = tid & 3;  // nl 0..63, kq*8: k-octet
  bf16x8 v = *(const bf16x8*)(&tile[nl][kq * 8]);
  *(bf16x8*)(wt + (size_t)(n0 + nl) * K + k0 + kq * 8) = v;
}

// ---------------- GEMM v2: BK=64 (2 sub-steps per barrier pair -> half the
// vmcnt(0)-drain stalls), flat grid + XCD swizzle, C = A @ Bt^T + bias -----
template <int TM>
__global__ __launch_bounds__(256) void gemm_kernel(
    const bf16* __restrict__ A, const bf16* __restrict__ Bt,
    const bf16* __restrict__ bias, bf16* __restrict__ outb,
    int M, int N, int K, int relu, int nbx) {
  constexpr int NI = TM / 32;
  constexpr int WM = TM / 2;
  constexpr int CA = TM / 64;
  __shared__ alignas(16) bf16 As[2][TM * 32];
  __shared__ alignas(16) bf16 Bs[2][128 * 32];
  int tid = threadIdx.x;
  int lane = tid & 63, wv = tid >> 6;
  int quad = lane >> 4, l15 = lane & 15;
  int wg = blockIdx.x;
  int w = (wg & 7) * (gridDim.x >> 3) + (wg >> 3);  // XCD-contiguous
  int bx = w % nbx, by = w / nbx;
  int m0 = by * TM, n0 = bx * 128;
  int wm = wv >> 1, wn = wv & 1;

  f32x4 acc[NI][4];
#pragma unroll
  for (int i = 0; i < NI; ++i)
#pragma unroll
    for (int j = 0; j < 4; ++j) acc[i][j] = (f32x4){0.f, 0.f, 0.f, 0.f};

  int sr = lane >> 2, sc = (lane & 3) * 8;
  const bf16* gA[CA];
  bf16* lA0[CA];
  bf16* lA1[CA];
#pragma unroll
  for (int t = 0; t < CA; ++t) {
    int ch = wv * CA + t;
    gA[t] = A + (size_t)(m0 + ch * 16 + sr) * K + sc;
    lA0[t] = As[0] + ch * 512 + lane * 8;
    lA1[t] = As[1] + ch * 512 + lane * 8;
  }
  const bf16* gB0 = Bt + (size_t)(n0 + (wv * 2) * 16 + sr) * K + sc;
  const bf16* gB1 = Bt + (size_t)(n0 + (wv * 2 + 1) * 16 + sr) * K + sc;
  bf16* lB00 = Bs[0] + (wv * 2) * 512 + lane * 8;
  bf16* lB01 = Bs[1] + (wv * 2) * 512 + lane * 8;
  bf16* lB10 = Bs[0] + (wv * 2 + 1) * 512 + lane * 8;
  bf16* lB11 = Bs[1] + (wv * 2 + 1) * 512 + lane * 8;

  for (int k0 = 0; k0 < K; k0 += 64) {
#pragma unroll
    for (int t = 0; t < CA; ++t) {
      gl_lds16(gA[t] + k0, lA0[t]);
      gl_lds16(gA[t] + k0 + 32, lA1[t]);
    }
    gl_lds16(gB0 + k0, lB00);
    gl_lds16(gB0 + k0 + 32, lB01);
    gl_lds16(gB1 + k0, lB10);
    gl_lds16(gB1 + k0 + 32, lB11);
    __syncthreads();
#pragma unroll
    for (int s = 0; s < 2; ++s) {
      bf16x8 af[NI], bfr[4];
#pragma unroll
      for (int i = 0; i < NI; ++i)
        af[i] = *(const bf16x8*)(As[s] + (wm * WM + i * 16 + l15) * 32 + quad * 8);
#pragma unroll
      for (int j = 0; j < 4; ++j)
        bfr[j] = *(const bf16x8*)(Bs[s] + (wn * 64 + j * 16 + l15) * 32 + quad * 8);
#pragma unroll
      for (int i = 0; i < NI; ++i)
#pragma unroll
        for (int j = 0; j < 4; ++j)
          acc[i][j] = __builtin_amdgcn_mfma_f32_16x16x32_bf16(af[i], bfr[j],
                                                              acc[i][j], 0, 0, 0);
    }
    __syncthreads();
  }

#pragma unroll
  for (int j = 0; j < 4; ++j) {
    int col = n0 + wn * 64 + j * 16 + l15;
    float bval = (float)bias[col];
#pragma unroll
    for (int i = 0; i < NI; ++i) {
      int rb = m0 + wm * WM + i * 16 + quad * 4;
#pragma unroll
      for (int r = 0; r < 4; ++r) {
        float v = acc[i][j][r] + bval;
        if (relu) v = fmaxf(v, 0.f);
        outb[(size_t)(rb + r) * N + col] = (bf16)v;
      }
    }
  }
}

// ---------------- split-K GEMM v2: BK=64, flat grid + XCD swizzle --------
__global__ __launch_bounds__(256) void gemm_splitk_kernel(
    const bf16* __restrict__ A, const bf16* __restrict__ Bt,
    float* __restrict__ pout, int M, int N, int KC, int Ktot, int nbx) {
  __shared__ alignas(16) bf16 As[2][128 * 32];
  __shared__ alignas(16) bf16 Bs[2][128 * 32];
  int tid = threadIdx.x;
  int lane = tid & 63, wv = tid >> 6;
  int quad = lane >> 4, l15 = lane & 15;
  int wg = blockIdx.x;
  int w = (wg & 7) * (gridDim.x >> 3) + (wg >> 3);  // XCD-contiguous
  int nxy = nbx * (M >> 7);
  int bz = w / nxy;
  int rem = w - bz * nxy;
  int bx = rem % nbx, by = rem / nbx;
  int m0 = by * 128, n0 = bx * 128;
  int wm = wv >> 1, wn = wv & 1;
  int kb = bz * KC;
  pout += (size_t)bz * M * N;

  f32x4 acc[4][4];
#pragma unroll
  for (int i = 0; i < 4; ++i)
#pragma unroll
    for (int j = 0; j < 4; ++j) acc[i][j] = (f32x4){0.f, 0.f, 0.f, 0.f};

  int sr = lane >> 2, sc = (lane & 3) * 8;
  const bf16* gA0 = A + (size_t)(m0 + (wv * 2) * 16 + sr) * Ktot + sc;
  const bf16* gA1 = A + (size_t)(m0 + (wv * 2 + 1) * 16 + sr) * Ktot + sc;
  const bf16* gB0 = Bt + (size_t)(n0 + (wv * 2) * 16 + sr) * Ktot + sc;
  const bf16* gB1 = Bt + (size_t)(n0 + (wv * 2 + 1) * 16 + sr) * Ktot + sc;
  bf16* lA00 = As[0] + (wv * 2) * 512 + lane * 8;
  bf16* lA01 = As[1] + (wv * 2) * 512 + lane * 8;
  bf16* lA10 = As[0] + (wv * 2 + 1) * 512 + lane * 8;
  bf16* lA11 = As[1] + (wv * 2 + 1) * 512 + lane * 8;
  bf16* lB00 = Bs[0] + (wv * 2) * 512 + lane * 8;
  bf16* lB01 = Bs[1] + (wv * 2) * 512 + lane * 8;
  bf16* lB10 = Bs[0] + (wv * 2 + 1) * 512 + lane * 8;
  bf16* lB11 = Bs[1] + (wv * 2 + 1) * 512 + lane * 8;

  for (int k0 = kb; k0 < kb + KC; k0 += 64) {
    gl_lds16(gA0 + k0, lA00);
    gl_lds16(gA0 + k0 + 32, lA01);
    gl_lds16(gA1 + k0, lA10);
    gl_lds16(gA1 + k0 + 32, lA11);
    gl_lds16(gB0 + k0, lB00);
    gl_lds16(gB0 + k0 + 32, lB01);
    gl_lds16(gB1 + k0, lB10);
    gl_lds16(gB1 + k0 + 32, lB11);
    __syncthreads();
#pragma unroll
    for (int s = 0; s < 2; ++s) {
      bf16x8 af[4], bfr[4];
#pragma unroll
      for (int i = 0; i < 4; ++i)
        af[i] = *(const bf16x8*)(As[s] + (wm * 64 + i * 16 + l15) * 32 + quad * 8);
#pragma unroll
      for (int j = 0; j < 4; ++j)
        bfr[j] = *(const bf16x8*)(Bs[s] + (wn * 64 + j * 16 + l15) * 32 + quad * 8);
#pragma unroll
      for (int i = 0; i < 4; ++i)
#pragma unroll
        for (int j = 0; j < 4; ++j)
          acc[i][j] = __builtin_amdgcn_mfma_f32_16x16x32_bf16(af[i], bfr[j],
                                                              acc[i][j], 0, 0, 0);
    }
    __syncthreads();
  }
#pragma unroll
  for (int j = 0; j < 4; ++j) {
    int col = n0 + wn * 64 + j * 16 + l15;
#pragma unroll
    for (int i = 0; i < 4; ++i) {
      int rb = m0 + wm * 64 + i * 16 + quad * 4;
#pragma unroll
      for (int r = 0; r < 4; ++r)
        pout[(size_t)(rb + r) * N + col] = acc[i][j][r];
    }
  }
}

// ---------------- V pre-transpose: [b][kv][h*64+d] -> [b*NH+h][d][skv] ----
__global__ __launch_bounds__(256) void vt_pre_kernel(
    const bf16* __restrict__ v, int vstride, bf16* __restrict__ vt, int skv) {
  __shared__ bf16 tile[32][33];
  int tid = threadIdx.x;
  int tx = tid & 31, ty = tid >> 5;
  int kv0 = blockIdx.x * 32, d0 = blockIdx.y * 32;
  int bh = blockIdx.z;
  int b = bh >> 4, h = bh & 15;
  const bf16* src = v + (size_t)b * skv * vstride + h * HDIM;
#pragma unroll
  for (int i = 0; i < 4; ++i)
    tile[ty + i * 8][tx] = src[(size_t)(kv0 + ty + i * 8) * vstride + d0 + tx];
  __syncthreads();
  bf16* dst = vt + ((size_t)bh * HDIM + d0) * skv + kv0;
#pragma unroll
  for (int i = 0; i < 4; ++i)
    dst[(size_t)(ty + i * 8) * skv + tx] = tile[tx][ty + i * 8];
}

// ---------------- flash v12: 6 blocks/CU operating point -------------------
// R8 lesson: (256,8) caps VGPR at 64 < kernel's ~100 live regs -> scratch
// spills -> 1.35GB HBM traffic. (256,6) caps at ~85 which FITS.
// Single-buffered K/V (16KB LDS), nsplit=3 -> grid 1536 = 6 blocks/CU
// = 24 waves/CU (1.5x R7). 2 barriers/chunk; cross-block TLP covers stalls.
__global__ __launch_bounds__(256, 6) void flash12_kernel(
    const bf16* __restrict__ Q, int qstride,
    const bf16* __restrict__ Kk, int kstride,
    const bf16* __restrict__ VT, bf16* __restrict__ ctx,
    float* __restrict__ opart, float* __restrict__ lpart,
    int skv, int causal, int nsplit) {
  __shared__ alignas(16) bf16 KTl[64 * 64];
  __shared__ alignas(16) bf16 VTl[64 * 64];
  int tid = threadIdx.x;
  int lane = tid & 63, wv = tid >> 6, quad = lane >> 4, l15 = lane & 15;
  int wg = blockIdx.x;
  int cpx = gridDim.x >> 3;
  int w = (wg & 7) * cpx + (wg >> 3);  // XCD-contiguous work id
  int qb = w & 15;
  int h = (w >> 4) & 15;
  int zz = w >> 8;
  int b = zz / nsplit;
  int half = zz - b * nsplit;
  int q0 = qb * 128;
  int qw = q0 + wv * 32;
  int l7 = l15 & 7;

  // Q as B-operand of QK^T; fold 0.125*log2(e) so softmax is pure v_exp
  bf16x8 qf[2][2];
  const float qsc = 0.125f * 1.44269504f;
#pragma unroll
  for (int a = 0; a < 2; ++a) {
    const bf16* qp = Q + (size_t)(b * SEQ + qw + a * 16 + l15) * qstride + h * HDIM;
    qf[a][0] = *(const bf16x8*)(qp + quad * 8);
    qf[a][1] = *(const bf16x8*)(qp + 32 + quad * 8);
#pragma unroll
    for (int j = 0; j < 8; ++j) {
      qf[a][0][j] = (bf16)((float)qf[a][0][j] * qsc);
      qf[a][1][j] = (bf16)((float)qf[a][1][j] * qsc);
    }
  }
  s16x4 onesA = {0x3F80, 0x3F80, 0x3F80, 0x3F80};  // bf16 1.0 x4

  // o^T accumulators: o[a][jt] rows = d-local (quad*4+r), col = q (l15)
  f32x4 o[2][4], oL[2];
#pragma unroll
  for (int a = 0; a < 2; ++a) {
    oL[a] = (f32x4){0.f, 0.f, 0.f, 0.f};
#pragma unroll
    for (int j = 0; j < 4; ++j) o[a][j] = (f32x4){0.f, 0.f, 0.f, 0.f};
  }

  int nch_tot = causal ? (q0 + 128) / 64 : skv / 64;
  int c_lo = (half * nch_tot) / nsplit;
  int c_hi = ((half + 1) * nch_tot) / nsplit;

  // staging geometry: wave wv owns tile rows [wv*16, wv*16+16), two 8-row
  // gl_lds ops each. Global source col-segment pre-swizzled so that the
  // LINEAR lds write lands data at physical slot (colseg ^ (row&7)).
  int l8 = lane >> 3;
  int colseg = (lane & 7) ^ l8;  // (row&7)==l8 for both ops (row0%8==0)
  int grow = wv * 16 + l8;
  const bf16* kbase = Kk + ((size_t)b * skv + grow) * kstride + h * HDIM + colseg * 8;
  const bf16* vbase = VT + ((size_t)(b * NH + h) * HDIM + grow) * skv + colseg * 8;
  bf16* kls = &KTl[wv * 1024];  // lane-uniform dest base (lane0 value)
  bf16* vls = &VTl[wv * 1024];

  auto STAGE = [&](int cc) {
    const bf16* ks = kbase + (size_t)(cc * 64) * kstride;
    const bf16* vs = vbase + cc * 64;
    gl_lds16(ks, kls);
    gl_lds16(ks + (size_t)8 * kstride, kls + 512);
    gl_lds16(vs, vls);
    gl_lds16(vs + (size_t)8 * skv, vls + 512);
  };

  for (int c = c_lo; c < c_hi; ++c) {
    int kv0 = c * 64;
    __syncthreads();  // WAR: all waves' reads of previous chunk complete
    STAGE(c);
    __syncthreads();  // RAW: barrier drains vmcnt -> K/V staged & visible

    if (!causal || kv0 <= qw + 31) {  // wave-uniform skip of masked chunks
      bf16x4 p[2][4];
      // S^T = K @ Q^T per 16-row kv tile t; convert to bf16 in-register
#pragma unroll
      for (int t = 0; t < 4; ++t) {
        const bf16* kb = KTl + (t * 16 + l15) * 64;
        bf16x8 kt0 = *(const bf16x8*)(kb + ((quad ^ l7) << 3));
        bf16x8 kt1 = *(const bf16x8*)(kb + (((quad + 4) ^ l7) << 3));
#pragma unroll
        for (int a = 0; a < 2; ++a) {
          f32x4 z = (f32x4){0.f, 0.f, 0.f, 0.f};
          z = __builtin_amdgcn_mfma_f32_16x16x32_bf16(kt0, qf[a][0], z, 0, 0, 0);
          z = __builtin_amdgcn_mfma_f32_16x16x32_bf16(kt1, qf[a][1], z, 0, 0, 0);
          if (causal && kv0 + 63 > qw) {  // diagonal region: element mask
#pragma unroll
            for (int r = 0; r < 4; ++r)
              if (kv0 + t * 16 + quad * 4 + r > qw + a * 16 + l15)
                z[r] = -1e30f;
          }
          bf16x4 pk;
#pragma unroll
          for (int r = 0; r < 4; ++r) pk[r] = (bf16)exp2f(z[r]);
          p[a][t] = pk;
          // row-sum via ones-A MFMA: every lane gets l[q=l15] in all rows
          oL[a] = __builtin_amdgcn_mfma_f32_16x16x16bf16_1k(
              onesA, as_s16x4(pk), oL[a], 0, 0, 0);
        }
      }
      // PV: o^T[d][q] += V^T-frag (A) x P^T-D-frag (B), 16x16x16
#pragma unroll
      for (int jt = 0; jt < 4; ++jt) {
        const bf16* vb = VTl + (jt * 16 + l15) * 64;
        bf16x4 af[4];
#pragma unroll
        for (int t = 0; t < 4; ++t)
          af[t] = *(const bf16x4*)(
              vb + ((((t * 2 + (quad >> 1)) ^ l7) << 3) + ((quad & 1) << 2)));
#pragma unroll
        for (int a = 0; a < 2; ++a)
#pragma unroll
          for (int t = 0; t < 4; ++t)
            o[a][jt] = __builtin_amdgcn_mfma_f32_16x16x16bf16_1k(
                as_s16x4(af[t]), as_s16x4(p[a][t]), o[a][jt], 0, 0, 0);
      }
    }
  }

  if (nsplit == 1) {
#pragma unroll
    for (int a = 0; a < 2; ++a) {
      float inv = 1.0f / fmaxf(oL[a][0], 1e-30f);
      bf16* cp = ctx + (size_t)(b * SEQ + qw + a * 16 + l15) * DM + h * HDIM + quad * 4;
#pragma unroll
      for (int jt = 0; jt < 4; ++jt) {
        bf16x4 ob = {(bf16)(o[a][jt][0] * inv), (bf16)(o[a][jt][1] * inv),
                     (bf16)(o[a][jt][2] * inv), (bf16)(o[a][jt][3] * inv)};
        *(bf16x4*)(cp + jt * 16) = ob;
      }
    }
  } else {
    // additive partials: fixed-shift softmax means o/l just sum across splits
#pragma unroll
    for (int a = 0; a < 2; ++a) {
      float* op = opart + (size_t)half * MR * DM +
                  (size_t)(b * SEQ + qw + a * 16 + l15) * DM + h * HDIM + quad * 4;
#pragma unroll
      for (int jt = 0; jt < 4; ++jt) *(f32x4*)(op + jt * 16) = o[a][jt];
      if (lane < 16)
        lpart[(size_t)((half * BB + b) * NH + h) * SEQ + qw + a * 16 + l15] =
            oL[a][0];
    }
  }
}

// ---------------- kv-split combine: ctx = sum(o_s) / sum(l_s) -------------
template <int NS>
__global__ __launch_bounds__(256) void flash_comb_kernel(
    const float* __restrict__ opart, const float* __restrict__ lpart,
    bf16* __restrict__ ctx) {
  int row = blockIdx.x, tid = threadIdx.x;
  int b = row >> 11, q = row & (SEQ - 1);
  int h = tid >> 4;
  float l = 0.f;
#pragma unroll
  for (int s = 0; s < NS; ++s)
    l += lpart[(size_t)((s * BB + b) * NH + h) * SEQ + q];
  float inv = 1.0f / fmaxf(l, 1e-30f);
  float a0 = 0.f, a1 = 0.f, a2 = 0.f, a3 = 0.f;
#pragma unroll
  for (int s = 0; s < NS; ++s) {
    f32x4 v = ((const f32x4*)(opart + (size_t)s * MR * DM + (size_t)row * DM))[tid];
    a0 += v[0]; a1 += v[1]; a2 += v[2]; a3 += v[3];
  }
  bf16x4 ob = {(bf16)(a0 * inv), (bf16)(a1 * inv),
               (bf16)(a2 * inv), (bf16)(a3 * inv)};
  ((bf16x4*)(ctx + (size_t)row * DM))[tid] = ob;
}

// ---------------- fused split-K reduce + bias + residual + LayerNorm ------
template <int NP>
__global__ __launch_bounds__(256) void addnorm_red_kernel(
    const bf16* __restrict__ res, const float* __restrict__ part,
    const bf16* __restrict__ bias, const bf16* __restrict__ g,
    const bf16* __restrict__ be, bf16* __restrict__ yb,
    void* __restrict__ outAny, const int* __restrict__ flag) {
  int row = blockIdx.x, tid = threadIdx.x;
  float a0 = 0.f, a1 = 0.f, a2 = 0.f, a3 = 0.f;
#pragma unroll
  for (int p = 0; p < NP; ++p) {
    float4 v = ((const float4*)(part + (size_t)p * MR * DM + (size_t)row * DM))[tid];
    a0 += v.x; a1 += v.y; a2 += v.z; a3 += v.w;
  }
  bf16x4 bb = ((const bf16x4*)bias)[tid];
  bf16x4 rr = ((const bf16x4*)(res + (size_t)row * DM))[tid];
  float s0 = (float)rr[0] + a0 + (float)bb[0];
  float s1 = (float)rr[1] + a1 + (float)bb[1];
  float s2 = (float)rr[2] + a2 + (float)bb[2];
  float s3 = (float)rr[3] + a3 + (float)bb[3];
  float sum = s0 + s1 + s2 + s3;
  float sq = s0 * s0 + s1 * s1 + s2 * s2 + s3 * s3;
#pragma unroll
  for (int mk = 32; mk >= 1; mk >>= 1) {
    sum += __shfl_xor(sum, mk, 64);
    sq += __shfl_xor(sq, mk, 64);
  }
  __shared__ float red[8];
  int wvi = tid >> 6, lane = tid & 63;
  if (lane == 0) { red[wvi * 2] = sum; red[wvi * 2 + 1] = sq; }
  __syncthreads();
  sum = red[0] + red[2] + red[4] + red[6];
  sq = red[1] + red[3] + red[5] + red[7];
  float mu = sum * (1.0f / DM);
  float var = sq * (1.0f / DM) - mu * mu;
  float rstd = rsqrtf(var + 1e-5f);
  bf16x4 g4 = ((const bf16x4*)g)[tid];
  bf16x4 b4 = ((const bf16x4*)be)[tid];
  float y0 = (s0 - mu) * rstd * (float)g4[0] + (float)b4[0];
  float y1 = (s1 - mu) * rstd * (float)g4[1] + (float)b4[1];
  float y2 = (s2 - mu) * rstd * (float)g4[2] + (float)b4[2];
  float y3 = (s3 - mu) * rstd * (float)g4[3] + (float)b4[3];
  if (yb) {
    bf16x4 ob = {(bf16)y0, (bf16)y1, (bf16)y2, (bf16)y3};
    ((bf16x4*)(yb + (size_t)row * DM))[tid] = ob;
  }
  if (outAny) {
    if (*flag) {
      bf16x4 ob = {(bf16)y0, (bf16)y1, (bf16)y2, (bf16)y3};
      ((bf16x4*)outAny)[(size_t)row * 256 + tid] = ob;
    } else {
      ((float4*)outAny)[(size_t)row * 256 + tid] = make_float4(y0, y1, y2, y3);
    }
  }
}

extern "C" void kernel_launch(void* const* d_in, const int* in_sizes, int n_in,
                              void* d_out, int out_size, void* d_ws, size_t ws_size,
                              hipStream_t stream) {
  (void)in_sizes; (void)n_in; (void)out_size; (void)ws_size;
  const void* x_raw   = d_in[0];
  const void* enc_raw = d_in[1];

  char* ws = (char*)d_ws;
  size_t off = 0;
  auto alloc = [&](size_t bytes) -> void* {
    void* p = ws + off;
    off += (bytes + 255) & ~(size_t)255;
    return p;
  };
  const size_t SB = (size_t)MR * DM;
  int* flag    = (int*)alloc(256);
  bf16* smallb = (bf16*)alloc(20480 * 2);
  bf16* wt   = (bf16*)alloc((size_t)16 * MEG * 2);
  bf16* xb   = (bf16*)alloc(SB * 2);
  bf16* encb = (bf16*)alloc(SB * 2);
  bf16* vtg  = (bf16*)alloc(SB * 2);
  bf16* ctx  = (bf16*)alloc(SB * 2);
  bf16* hb1  = (bf16*)alloc(SB * 2);
  bf16* hb2  = (bf16*)alloc(SB * 2);
  bf16* qkv  = (bf16*)alloc(SB * 3 * 2);
  bf16* kvc  = (bf16*)alloc(SB * 2 * 2);
  float* part = (float*)alloc(SB * 4 * 4);
  float* lpart = (float*)alloc((size_t)4 * BB * NH * SEQ * 4);
  bf16* gbuf = qkv;
  bf16* qc   = xb;

  bf16* b_qkvs = smallb + 0;     bf16* b_os  = smallb + 3072;
  bf16* b_qc   = smallb + 4096;  bf16* b_kvc = smallb + 5120;
  bf16* b_oc   = smallb + 7168;  bf16* b_f1  = smallb + 8192;
  bf16* b_f2   = smallb + 12288;
  bf16* l1g = smallb + 13312; bf16* l1b = smallb + 14336;
  bf16* l2g = smallb + 15360; bf16* l2b = smallb + 16384;
  bf16* l3g = smallb + 17408; bf16* l3b = smallb + 18432;

  detect_kernel<<<1, 64, 0, stream>>>((const unsigned int*)x_raw, flag);
  cvt_big_kernel<<<(int)(SB / 1024), 256, 0, stream>>>(x_raw, xb, (int)(SB / 4), flag);
  cvt_big_kernel<<<(int)(SB / 1024), 256, 0, stream>>>(enc_raw, encb, (int)(SB / 4), flag);
  P16 ps;
  ps.p[0] = d_in[5];  ps.p[1] = d_in[7];  ps.p[2] = d_in[9];  ps.p[3] = d_in[11];
  ps.p[4] = d_in[13]; ps.p[5] = d_in[15]; ps.p[6] = d_in[17]; ps.p[7] = d_in[19];
  ps.p[8] = d_in[21]; ps.p[9] = d_in[23];
  ps.p[10] = d_in[24]; ps.p[11] = d_in[25]; ps.p[12] = d_in[26];
  ps.p[13] = d_in[27]; ps.p[14] = d_in[28]; ps.p[15] = d_in[29];
  cvt_small_kernel<<<16, 256, 0, stream>>>(ps, smallb, flag);

  WTB wb;
  const int wsrc[10] = {4, 6, 8, 10, 12, 14, 16, 18, 20, 22};
  for (int i = 0; i < 10; ++i) {
    wb.src[i] = d_in[wsrc[i]];
    wb.K[i] = 1024; wb.N[i] = 1024;
    wb.dstoff[i] = i * MEG;
  }
  wb.N[8] = 4096;
  wb.K[9] = 4096; wb.dstoff[9] = 12 * MEG;
  int bacc = 0;
  for (int i = 0; i < 10; ++i) {
    wb.bstart[i] = bacc;
    bacc += (wb.N[i] / 64) * (wb.K[i] / 32);
  }
  wt_all_kernel<<<bacc, 256, 0, stream>>>(wb, wt, flag);

  // ---- self attention (causal, kv-split x3 + additive combine) ----
  gemm_kernel<128><<<24 * 32, 256, 0, stream>>>(xb, wt, b_qkvs, qkv,
                                                MR, 3072, DM, 0, 24);
  vt_pre_kernel<<<dim3(SEQ / 32, 2, 32), 256, 0, stream>>>(qkv + 2048, 3072, vtg, SEQ);
  flash12_kernel<<<16 * 16 * BB * 3, 256, 0, stream>>>(
      qkv, 3072, qkv + 1024, 3072, vtg, ctx, part, lpart, SEQ, 1, 3);
  flash_comb_kernel<3><<<MR, 256, 0, stream>>>(part, lpart, ctx);
  gemm_splitk_kernel<<<8 * 32 * 2, 256, 0, stream>>>(
      ctx, wt + (size_t)3 * MEG, part, MR, DM, 512, DM, 8);
  addnorm_red_kernel<2><<<MR, 256, 0, stream>>>(xb, part, b_os, l1g, l1b,
                                                hb1, nullptr, flag);
  // ---- cross attention (kv-split x3 + additive combine) ----
  gemm_kernel<64><<<8 * 64, 256, 0, stream>>>(hb1, wt + (size_t)4 * MEG,
                                              b_qc, qc, MR, DM, DM, 0, 8);
  gemm_kernel<128><<<16 * 32, 256, 0, stream>>>(encb, wt + (size_t)5 * MEG,
                                                b_kvc, kvc, MR, 2048, DM, 0, 16);
  vt_pre_kernel<<<dim3(SEQ / 32, 2, 32), 256, 0, stream>>>(kvc + 1024, 2048, vtg, SEQ);
  flash12_kernel<<<16 * 16 * BB * 3, 256, 0, stream>>>(
      qc, 1024, kvc, 2048, vtg, ctx, part, lpart, SEQ, 0, 3);
  flash_comb_kernel<3><<<MR, 256, 0, stream>>>(part, lpart, ctx);
  gemm_splitk_kernel<<<8 * 32 * 2, 256, 0, stream>>>(
      ctx, wt + (size_t)7 * MEG, part, MR, DM, 512, DM, 8);
  addnorm_red_kernel<2><<<MR, 256, 0, stream>>>(hb1, part, b_oc, l2g, l2b,
                                                hb2, nullptr, flag);
  // ---- FFN ----
  gemm_kernel<128><<<32 * 32, 256, 0, stream>>>(hb2, wt + (size_t)8 * MEG,
                                                b_f1, gbuf, MR, DFF, DM, 1, 32);
  gemm_splitk_kernel<<<8 * 32 * 4, 256, 0, stream>>>(
      gbuf, wt + (size_t)12 * MEG, part, MR, DM, 1024, DFF, 8);
  addnorm_red_kernel<4><<<MR, 256, 0, stream>>>(hb2, part, b_f2, l3g, l3b,
                                                nullptr, d_out, flag);
}

// Round 10
// 633.981 us; speedup vs baseline: 1.7677x; 1.3658x over previous
//
#include <hip/hip_runtime.h>
#include <stdint.h>

typedef __bf16 bf16;
typedef __attribute__((ext_vector_type(4))) float f32x4;
typedef __attribute__((ext_vector_type(8))) __bf16 bf16x8;
typedef __attribute__((ext_vector_type(4))) __bf16 bf16x4;
typedef __attribute__((ext_vector_type(4))) short s16x4;

#define DM   1024
#define NH   16
#define HDIM 64
#define BB   2
#define SEQ  2048
#define MR   (BB * SEQ)
#define DFF  4096
#define MEG  (1024 * 1024)

// ---------------- dtype detection: 1 = bf16, 0 = f32 ----------------
__global__ void detect_kernel(const unsigned int* __restrict__ xw,
                              int* __restrict__ flag) {
  int tid = threadIdx.x;
  int bad = 0;
  for (int i = tid; i < 4096; i += 64) {
    unsigned int w = xw[i];
    float flo = __uint_as_float((w & 0xffffu) << 16);
    if (!(fabsf(flo) < 100.f)) bad = 1;
  }
  unsigned long long m = __ballot(bad);
  if (tid == 0) *flag = (m == 0ull) ? 1 : 0;
}

// ---------------- input canonicalization -> bf16 (both tensors, 1 launch) --
__global__ __launch_bounds__(256) void cvt_big2_kernel(
    const void* __restrict__ src0, bf16* __restrict__ dst0,
    const void* __restrict__ src1, bf16* __restrict__ dst1,
    int n4, const int* __restrict__ flag) {
  int i = blockIdx.x * 256 + threadIdx.x;
  if (i >= n4) return;
  const void* src = blockIdx.y ? src1 : src0;
  bf16* dst = blockIdx.y ? dst1 : dst0;
  if (*flag) {
    ((bf16x4*)dst)[i] = ((const bf16x4*)src)[i];
  } else {
    float4 v = ((const float4*)src)[i];
    bf16x4 o = {(bf16)v.x, (bf16)v.y, (bf16)v.z, (bf16)v.w};
    ((bf16x4*)dst)[i] = o;
  }
}

struct P16 { const void* p[16]; };
__global__ __launch_bounds__(256) void cvt_small_kernel(
    P16 ps, bf16* __restrict__ dstbase, const int* __restrict__ flag) {
  const int ncnt[16] = {1024,1024,1024,1024,1024,1024,1024,1024,
                        4096,1024,1024,1024,1024,1024,1024,1024};
  const int doff[16] = {0,1024,2048,3072,4096,5120,6144,7168,
                        8192,12288,13312,14336,15360,16384,17408,18432};
  int b = blockIdx.x;
  int n = ncnt[b];
  bool isbf = (*flag) != 0;
  const void* s = ps.p[b];
  bf16* d = dstbase + doff[b];
  for (int i = threadIdx.x; i * 4 < n; i += 256) {
    if (isbf) {
      ((bf16x4*)d)[i] = ((const bf16x4*)s)[i];
    } else {
      float4 v = ((const float4*)s)[i];
      bf16x4 o = {(bf16)v.x, (bf16)v.y, (bf16)v.z, (bf16)v.w};
      ((bf16x4*)d)[i] = o;
    }
  }
}

// ---------------- async global->LDS, 16B per lane ----------------
static __device__ __forceinline__ void gl_lds16(const bf16* g, bf16* l) {
  auto gp = reinterpret_cast<__attribute__((address_space(1))) unsigned int*>(
      reinterpret_cast<uintptr_t>(g));
  auto lp = reinterpret_cast<__attribute__((address_space(3))) unsigned int*>(
      (unsigned int)reinterpret_cast<uintptr_t>(l));
  __builtin_amdgcn_global_load_lds(gp, lp, 16, 0, 0);
}

static __device__ __forceinline__ s16x4 as_s16x4(bf16x4 v) {
  s16x4 r;
  __builtin_memcpy(&r, &v, 8);
  return r;
}

// ---------------- batched weight transpose v2: 64x32 tiles, u32 loads,
// b128 stores. wt[n][k] = w[k][n]. ----------------------------------------
struct WTB {
  const void* src[10];
  int dstoff[10];
  int K[10], N[10];
  int bstart[10];
};
__global__ __launch_bounds__(256) void wt_all_kernel(WTB wb, bf16* __restrict__ wtbase,
                                                     const int* __restrict__ flag) {
  __shared__ alignas(16) bf16 tile[64][40];  // 80B rows: 16B-aligned
  int bid = blockIdx.x;
  int wi = 0;
  while (wi < 9 && bid >= wb.bstart[wi + 1]) ++wi;
  int rel = bid - wb.bstart[wi];
  int N = wb.N[wi], K = wb.K[wi];
  int nb = N >> 6;
  int n0 = (rel % nb) * 64, k0 = (rel / nb) * 32;
  const void* w = wb.src[wi];
  bf16* wt = wtbase + wb.dstoff[wi];
  bool isbf = (*flag) != 0;
  int tid = threadIdx.x;
  int np = tid & 31, tk = tid >> 5;  // np: n-pair 0..31, tk: k-row base 0..7
#pragma unroll
  for (int i = 0; i < 4; ++i) {
    int kl = tk + i * 8;
    bf16 b0, b1;
    if (isbf) {
      unsigned int u = *(const unsigned int*)(
          (const bf16*)w + (size_t)(k0 + kl) * N + n0 + np * 2);
      unsigned short s0 = (unsigned short)(u & 0xffffu);
      unsigned short s1 = (unsigned short)(u >> 16);
      __builtin_memcpy(&b0, &s0, 2);
      __builtin_memcpy(&b1, &s1, 2);
    } else {
      const float* fp = (const float*)w + (size_t)(k0 + kl) * N + n0 + np * 2;
      b0 = (bf16)fp[0];
      b1 = (bf16)fp[1];
    }
    tile[np * 2][kl] = b0;
    tile[np * 2 + 1][kl] = b1;
  }
  __syncthreads();
  int nl = tid >> 2, kq = tid & 3;  // nl 0..63, kq*8: k-octet
  bf16x8 v = *(const bf16x8*)(&tile[nl][kq * 8]);
  *(bf16x8*)(wt + (size_t)(n0 + nl) * K + k0 + kq * 8) = v;
}

// ---------------- GEMM v2: BK=64 (2 sub-steps per barrier pair -> half the
// vmcnt(0)-drain stalls), flat grid + XCD swizzle, C = A @ Bt^T + bias -----
template <int TM>
__global__ __launch_bounds__(256) void gemm_kernel(
    const bf16* __restrict__ A, const bf16* __restrict__ Bt,
    const bf16* __restrict__ bias, bf16* __restrict__ outb,
    int M, int N, int K, int relu, int nbx) {
  constexpr int NI = TM / 32;
  constexpr int WM = TM / 2;
  constexpr int CA = TM / 64;
  __shared__ alignas(16) bf16 As[2][TM * 32];
  __shared__ alignas(16) bf16 Bs[2][128 * 32];
  int tid = threadIdx.x;
  int lane = tid & 63, wv = tid >> 6;
  int quad = lane >> 4, l15 = lane & 15;
  int wg = blockIdx.x;
  int w = (wg & 7) * (gridDim.x >> 3) + (wg >> 3);  // XCD-contiguous
  int bx = w % nbx, by = w / nbx;
  int m0 = by * TM, n0 = bx * 128;
  int wm = wv >> 1, wn = wv & 1;

  f32x4 acc[NI][4];
#pragma unroll
  for (int i = 0; i < NI; ++i)
#pragma unroll
    for (int j = 0; j < 4; ++j) acc[i][j] = (f32x4){0.f, 0.f, 0.f, 0.f};

  int sr = lane >> 2, sc = (lane & 3) * 8;
  const bf16* gA[CA];
  bf16* lA0[CA];
  bf16* lA1[CA];
#pragma unroll
  for (int t = 0; t < CA; ++t) {
    int ch = wv * CA + t;
    gA[t] = A + (size_t)(m0 + ch * 16 + sr) * K + sc;
    lA0[t] = As[0] + ch * 512 + lane * 8;
    lA1[t] = As[1] + ch * 512 + lane * 8;
  }
  const bf16* gB0 = Bt + (size_t)(n0 + (wv * 2) * 16 + sr) * K + sc;
  const bf16* gB1 = Bt + (size_t)(n0 + (wv * 2 + 1) * 16 + sr) * K + sc;
  bf16* lB00 = Bs[0] + (wv * 2) * 512 + lane * 8;
  bf16* lB01 = Bs[1] + (wv * 2) * 512 + lane * 8;
  bf16* lB10 = Bs[0] + (wv * 2 + 1) * 512 + lane * 8;
  bf16* lB11 = Bs[1] + (wv * 2 + 1) * 512 + lane * 8;

  for (int k0 = 0; k0 < K; k0 += 64) {
#pragma unroll
    for (int t = 0; t < CA; ++t) {
      gl_lds16(gA[t] + k0, lA0[t]);
      gl_lds16(gA[t] + k0 + 32, lA1[t]);
    }
    gl_lds16(gB0 + k0, lB00);
    gl_lds16(gB0 + k0 + 32, lB01);
    gl_lds16(gB1 + k0, lB10);
    gl_lds16(gB1 + k0 + 32, lB11);
    __syncthreads();
#pragma unroll
    for (int s = 0; s < 2; ++s) {
      bf16x8 af[NI], bfr[4];
#pragma unroll
      for (int i = 0; i < NI; ++i)
        af[i] = *(const bf16x8*)(As[s] + (wm * WM + i * 16 + l15) * 32 + quad * 8);
#pragma unroll
      for (int j = 0; j < 4; ++j)
        bfr[j] = *(const bf16x8*)(Bs[s] + (wn * 64 + j * 16 + l15) * 32 + quad * 8);
#pragma unroll
      for (int i = 0; i < NI; ++i)
#pragma unroll
        for (int j = 0; j < 4; ++j)
          acc[i][j] = __builtin_amdgcn_mfma_f32_16x16x32_bf16(af[i], bfr[j],
                                                              acc[i][j], 0, 0, 0);
    }
    __syncthreads();
  }

#pragma unroll
  for (int j = 0; j < 4; ++j) {
    int col = n0 + wn * 64 + j * 16 + l15;
    float bval = (float)bias[col];
#pragma unroll
    for (int i = 0; i < NI; ++i) {
      int rb = m0 + wm * WM + i * 16 + quad * 4;
#pragma unroll
      for (int r = 0; r < 4; ++r) {
        float v = acc[i][j][r] + bval;
        if (relu) v = fmaxf(v, 0.f);
        outb[(size_t)(rb + r) * N + col] = (bf16)v;
      }
    }
  }
}

// ---------------- split-K GEMM v2: BK=64, flat grid + XCD swizzle --------
__global__ __launch_bounds__(256) void gemm_splitk_kernel(
    const bf16* __restrict__ A, const bf16* __restrict__ Bt,
    float* __restrict__ pout, int M, int N, int KC, int Ktot, int nbx) {
  __shared__ alignas(16) bf16 As[2][128 * 32];
  __shared__ alignas(16) bf16 Bs[2][128 * 32];
  int tid = threadIdx.x;
  int lane = tid & 63, wv = tid >> 6;
  int quad = lane >> 4, l15 = lane & 15;
  int wg = blockIdx.x;
  int w = (wg & 7) * (gridDim.x >> 3) + (wg >> 3);  // XCD-contiguous
  int nxy = nbx * (M >> 7);
  int bz = w / nxy;
  int rem = w - bz * nxy;
  int bx = rem % nbx, by = rem / nbx;
  int m0 = by * 128, n0 = bx * 128;
  int wm = wv >> 1, wn = wv & 1;
  int kb = bz * KC;
  pout += (size_t)bz * M * N;

  f32x4 acc[4][4];
#pragma unroll
  for (int i = 0; i < 4; ++i)
#pragma unroll
    for (int j = 0; j < 4; ++j) acc[i][j] = (f32x4){0.f, 0.f, 0.f, 0.f};

  int sr = lane >> 2, sc = (lane & 3) * 8;
  const bf16* gA0 = A + (size_t)(m0 + (wv * 2) * 16 + sr) * Ktot + sc;
  const bf16* gA1 = A + (size_t)(m0 + (wv * 2 + 1) * 16 + sr) * Ktot + sc;
  const bf16* gB0 = Bt + (size_t)(n0 + (wv * 2) * 16 + sr) * Ktot + sc;
  const bf16* gB1 = Bt + (size_t)(n0 + (wv * 2 + 1) * 16 + sr) * Ktot + sc;
  bf16* lA00 = As[0] + (wv * 2) * 512 + lane * 8;
  bf16* lA01 = As[1] + (wv * 2) * 512 + lane * 8;
  bf16* lA10 = As[0] + (wv * 2 + 1) * 512 + lane * 8;
  bf16* lA11 = As[1] + (wv * 2 + 1) * 512 + lane * 8;
  bf16* lB00 = Bs[0] + (wv * 2) * 512 + lane * 8;
  bf16* lB01 = Bs[1] + (wv * 2) * 512 + lane * 8;
  bf16* lB10 = Bs[0] + (wv * 2 + 1) * 512 + lane * 8;
  bf16* lB11 = Bs[1] + (wv * 2 + 1) * 512 + lane * 8;

  for (int k0 = kb; k0 < kb + KC; k0 += 64) {
    gl_lds16(gA0 + k0, lA00);
    gl_lds16(gA0 + k0 + 32, lA01);
    gl_lds16(gA1 + k0, lA10);
    gl_lds16(gA1 + k0 + 32, lA11);
    gl_lds16(gB0 + k0, lB00);
    gl_lds16(gB0 + k0 + 32, lB01);
    gl_lds16(gB1 + k0, lB10);
    gl_lds16(gB1 + k0 + 32, lB11);
    __syncthreads();
#pragma unroll
    for (int s = 0; s < 2; ++s) {
      bf16x8 af[4], bfr[4];
#pragma unroll
      for (int i = 0; i < 4; ++i)
        af[i] = *(const bf16x8*)(As[s] + (wm * 64 + i * 16 + l15) * 32 + quad * 8);
#pragma unroll
      for (int j = 0; j < 4; ++j)
        bfr[j] = *(const bf16x8*)(Bs[s] + (wn * 64 + j * 16 + l15) * 32 + quad * 8);
#pragma unroll
      for (int i = 0; i < 4; ++i)
#pragma unroll
        for (int j = 0; j < 4; ++j)
          acc[i][j] = __builtin_amdgcn_mfma_f32_16x16x32_bf16(af[i], bfr[j],
                                                              acc[i][j], 0, 0, 0);
    }
    __syncthreads();
  }
#pragma unroll
  for (int j = 0; j < 4; ++j) {
    int col = n0 + wn * 64 + j * 16 + l15;
#pragma unroll
    for (int i = 0; i < 4; ++i) {
      int rb = m0 + wm * 64 + i * 16 + quad * 4;
#pragma unroll
      for (int r = 0; r < 4; ++r)
        pout[(size_t)(rb + r) * N + col] = acc[i][j][r];
    }
  }
}

// ---------------- V pre-transpose: [b][kv][h*64+d] -> [b*NH+h][d][skv] ----
__global__ __launch_bounds__(256) void vt_pre_kernel(
    const bf16* __restrict__ v, int vstride, bf16* __restrict__ vt, int skv) {
  __shared__ bf16 tile[32][33];
  int tid = threadIdx.x;
  int tx = tid & 31, ty = tid >> 5;
  int kv0 = blockIdx.x * 32, d0 = blockIdx.y * 32;
  int bh = blockIdx.z;
  int b = bh >> 4, h = bh & 15;
  const bf16* src = v + (size_t)b * skv * vstride + h * HDIM;
#pragma unroll
  for (int i = 0; i < 4; ++i)
    tile[ty + i * 8][tx] = src[(size_t)(kv0 + ty + i * 8) * vstride + d0 + tx];
  __syncthreads();
  bf16* dst = vt + ((size_t)bh * HDIM + d0) * skv + kv0;
#pragma unroll
  for (int i = 0; i < 4; ++i)
    dst[(size_t)(ty + i * 8) * skv + tx] = tile[tx][ty + i * 8];
}

// ---------------- flash v9 (R7 known-good binary): no LDS P, XOR-swizzled
// K/V via global_load_lds, dbuf 32KB LDS, 1 barrier/chunk, XCD swizzle.
// R10: SAME CODE, grid 2560 (nsplit=5). VGPR=64 + LDS 32KB -> HW residency
// 5 blocks/CU (launch_bounds(256,4) is a compiler floor, not a runtime cap).
__global__ __launch_bounds__(256, 4) void flash9_kernel(
    const bf16* __restrict__ Q, int qstride,
    const bf16* __restrict__ Kk, int kstride,
    const bf16* __restrict__ VT, bf16* __restrict__ ctx,
    float* __restrict__ opart, float* __restrict__ lpart,
    int skv, int causal, int nsplit) {
  __shared__ alignas(16) bf16 KTl[2][64 * 64];
  __shared__ alignas(16) bf16 VTl[2][64 * 64];
  int tid = threadIdx.x;
  int lane = tid & 63, wv = tid >> 6, quad = lane >> 4, l15 = lane & 15;
  int wg = blockIdx.x;
  int cpx = gridDim.x >> 3;
  int w = (wg & 7) * cpx + (wg >> 3);  // XCD-contiguous work id
  int qb = w & 15;
  int h = (w >> 4) & 15;
  int zz = w >> 8;
  int b = zz / nsplit;
  int half = zz - b * nsplit;
  int q0 = qb * 128;
  int qw = q0 + wv * 32;
  int l7 = l15 & 7;

  // Q as B-operand of QK^T; fold 0.125*log2(e) so softmax is pure v_exp
  bf16x8 qf[2][2];
  const float qsc = 0.125f * 1.44269504f;
#pragma unroll
  for (int a = 0; a < 2; ++a) {
    const bf16* qp = Q + (size_t)(b * SEQ + qw + a * 16 + l15) * qstride + h * HDIM;
    qf[a][0] = *(const bf16x8*)(qp + quad * 8);
    qf[a][1] = *(const bf16x8*)(qp + 32 + quad * 8);
#pragma unroll
    for (int j = 0; j < 8; ++j) {
      qf[a][0][j] = (bf16)((float)qf[a][0][j] * qsc);
      qf[a][1][j] = (bf16)((float)qf[a][1][j] * qsc);
    }
  }
  s16x4 onesA = {0x3F80, 0x3F80, 0x3F80, 0x3F80};  // bf16 1.0 x4

  // o^T accumulators: o[a][jt] rows = d-local (quad*4+r), col = q (l15)
  f32x4 o[2][4], oL[2];
#pragma unroll
  for (int a = 0; a < 2; ++a) {
    oL[a] = (f32x4){0.f, 0.f, 0.f, 0.f};
#pragma unroll
    for (int j = 0; j < 4; ++j) o[a][j] = (f32x4){0.f, 0.f, 0.f, 0.f};
  }

  int nch_tot = causal ? (q0 + 128) / 64 : skv / 64;
  int c_lo = (half * nch_tot) / nsplit;
  int c_hi = ((half + 1) * nch_tot) / nsplit;

  // staging geometry: wave wv owns tile rows [wv*16, wv*16+16), two 8-row
  // gl_lds ops each. Global source col-segment pre-swizzled so that the
  // LINEAR lds write lands data at physical slot (colseg ^ (row&7)).
  int l8 = lane >> 3;
  int colseg = (lane & 7) ^ l8;  // (row&7)==l8 for both ops (row0%8==0)
  int grow = wv * 16 + l8;
  const bf16* kbase = Kk + ((size_t)b * skv + grow) * kstride + h * HDIM + colseg * 8;
  const bf16* vbase = VT + ((size_t)(b * NH + h) * HDIM + grow) * skv + colseg * 8;
  bf16* kls = &KTl[0][wv * 1024];  // lane-uniform dest base (lane0 value)
  bf16* vls = &VTl[0][wv * 1024];

  auto STAGE = [&](int bb, int cc) {
    const bf16* ks = kbase + (size_t)(cc * 64) * kstride;
    const bf16* vs = vbase + cc * 64;
    bf16* kd = kls + bb * 4096;
    bf16* vd = vls + bb * 4096;
    gl_lds16(ks, kd);
    gl_lds16(ks + (size_t)8 * kstride, kd + 512);
    gl_lds16(vs, vd);
    gl_lds16(vs + (size_t)8 * skv, vd + 512);
  };

  if (c_lo < c_hi) STAGE(0, c_lo);

  for (int c = c_lo; c < c_hi; ++c) {
    int cur = (c - c_lo) & 1;
    int kv0 = c * 64;
    __syncthreads();  // drains vmcnt -> buf[cur] staged; closes prev compute
    if (c + 1 < c_hi) STAGE(cur ^ 1, c + 1);  // in flight across this chunk

    if (!causal || kv0 <= qw + 31) {  // wave-uniform skip of masked chunks
      const bf16* kt_base = &KTl[0][0] + cur * 4096;
      const bf16* vt_base = &VTl[0][0] + cur * 4096;
      bf16x4 p[2][4];
      // S^T = K @ Q^T per 16-row kv tile t; convert to bf16 in-register
#pragma unroll
      for (int t = 0; t < 4; ++t) {
        const bf16* kb = kt_base + (t * 16 + l15) * 64;
        bf16x8 kt0 = *(const bf16x8*)(kb + ((quad ^ l7) << 3));
        bf16x8 kt1 = *(const bf16x8*)(kb + (((quad + 4) ^ l7) << 3));
#pragma unroll
        for (int a = 0; a < 2; ++a) {
          f32x4 z = (f32x4){0.f, 0.f, 0.f, 0.f};
          z = __builtin_amdgcn_mfma_f32_16x16x32_bf16(kt0, qf[a][0], z, 0, 0, 0);
          z = __builtin_amdgcn_mfma_f32_16x16x32_bf16(kt1, qf[a][1], z, 0, 0, 0);
          if (causal && kv0 + 63 > qw) {  // diagonal region: element mask
#pragma unroll
            for (int r = 0; r < 4; ++r)
              if (kv0 + t * 16 + quad * 4 + r > qw + a * 16 + l15)
                z[r] = -1e30f;
          }
          bf16x4 pk;
#pragma unroll
          for (int r = 0; r < 4; ++r) pk[r] = (bf16)exp2f(z[r]);
          p[a][t] = pk;
          // row-sum via ones-A MFMA: every lane gets l[q=l15] in all rows
          oL[a] = __builtin_amdgcn_mfma_f32_16x16x16bf16_1k(
              onesA, as_s16x4(pk), oL[a], 0, 0, 0);
        }
      }
      // PV: o^T[d][q] += V^T-frag (A) x P^T-D-frag (B), 16x16x16
#pragma unroll
      for (int jt = 0; jt < 4; ++jt) {
        const bf16* vb = vt_base + (jt * 16 + l15) * 64;
        bf16x4 af[4];
#pragma unroll
        for (int t = 0; t < 4; ++t)
          af[t] = *(const bf16x4*)(
              vb + ((((t * 2 + (quad >> 1)) ^ l7) << 3) + ((quad & 1) << 2)));
#pragma unroll
        for (int a = 0; a < 2; ++a)
#pragma unroll
          for (int t = 0; t < 4; ++t)
            o[a][jt] = __builtin_amdgcn_mfma_f32_16x16x16bf16_1k(
                as_s16x4(af[t]), as_s16x4(p[a][t]), o[a][jt], 0, 0, 0);
      }
    }
  }

  if (nsplit == 1) {
#pragma unroll
    for (int a = 0; a < 2; ++a) {
      float inv = 1.0f / fmaxf(oL[a][0], 1e-30f);
      bf16* cp = ctx + (size_t)(b * SEQ + qw + a * 16 + l15) * DM + h * HDIM + quad * 4;
#pragma unroll
      for (int jt = 0; jt < 4; ++jt) {
        bf16x4 ob = {(bf16)(o[a][jt][0] * inv), (bf16)(o[a][jt][1] * inv),
                     (bf16)(o[a][jt][2] * inv), (bf16)(o[a][jt][3] * inv)};
        *(bf16x4*)(cp + jt * 16) = ob;
      }
    }
  } else {
    // additive partials: fixed-shift softmax means o/l just sum across splits
#pragma unroll
    for (int a = 0; a < 2; ++a) {
      float* op = opart + (size_t)half * MR * DM +
                  (size_t)(b * SEQ + qw + a * 16 + l15) * DM + h * HDIM + quad * 4;
#pragma unroll
      for (int jt = 0; jt < 4; ++jt) *(f32x4*)(op + jt * 16) = o[a][jt];
      if (lane < 16)
        lpart[(size_t)((half * BB + b) * NH + h) * SEQ + qw + a * 16 + l15] =
            oL[a][0];
    }
  }
}

// ---------------- kv-split combine: ctx = sum(o_s) / sum(l_s) -------------
template <int NS>
__global__ __launch_bounds__(256) void flash_comb_kernel(
    const float* __restrict__ opart, const float* __restrict__ lpart,
    bf16* __restrict__ ctx) {
  int row = blockIdx.x, tid = threadIdx.x;
  int b = row >> 11, q = row & (SEQ - 1);
  int h = tid >> 4;
  float l = 0.f;
#pragma unroll
  for (int s = 0; s < NS; ++s)
    l += lpart[(size_t)((s * BB + b) * NH + h) * SEQ + q];
  float inv = 1.0f / fmaxf(l, 1e-30f);
  float a0 = 0.f, a1 = 0.f, a2 = 0.f, a3 = 0.f;
#pragma unroll
  for (int s = 0; s < NS; ++s) {
    f32x4 v = ((const f32x4*)(opart + (size_t)s * MR * DM + (size_t)row * DM))[tid];
    a0 += v[0]; a1 += v[1]; a2 += v[2]; a3 += v[3];
  }
  bf16x4 ob = {(bf16)(a0 * inv), (bf16)(a1 * inv),
               (bf16)(a2 * inv), (bf16)(a3 * inv)};
  ((bf16x4*)(ctx + (size_t)row * DM))[tid] = ob;
}

// ---------------- fused split-K reduce + bias + residual + LayerNorm ------
template <int NP>
__global__ __launch_bounds__(256) void addnorm_red_kernel(
    const bf16* __restrict__ res, const float* __restrict__ part,
    const bf16* __restrict__ bias, const bf16* __restrict__ g,
    const bf16* __restrict__ be, bf16* __restrict__ yb,
    void* __restrict__ outAny, const int* __restrict__ flag) {
  int row = blockIdx.x, tid = threadIdx.x;
  float a0 = 0.f, a1 = 0.f, a2 = 0.f, a3 = 0.f;
#pragma unroll
  for (int p = 0; p < NP; ++p) {
    float4 v = ((const float4*)(part + (size_t)p * MR * DM + (size_t)row * DM))[tid];
    a0 += v.x; a1 += v.y; a2 += v.z; a3 += v.w;
  }
  bf16x4 bb = ((const bf16x4*)bias)[tid];
  bf16x4 rr = ((const bf16x4*)(res + (size_t)row * DM))[tid];
  float s0 = (float)rr[0] + a0 + (float)bb[0];
  float s1 = (float)rr[1] + a1 + (float)bb[1];
  float s2 = (float)rr[2] + a2 + (float)bb[2];
  float s3 = (float)rr[3] + a3 + (float)bb[3];
  float sum = s0 + s1 + s2 + s3;
  float sq = s0 * s0 + s1 * s1 + s2 * s2 + s3 * s3;
#pragma unroll
  for (int mk = 32; mk >= 1; mk >>= 1) {
    sum += __shfl_xor(sum, mk, 64);
    sq += __shfl_xor(sq, mk, 64);
  }
  __shared__ float red[8];
  int wvi = tid >> 6, lane = tid & 63;
  if (lane == 0) { red[wvi * 2] = sum; red[wvi * 2 + 1] = sq; }
  __syncthreads();
  sum = red[0] + red[2] + red[4] + red[6];
  sq = red[1] + red[3] + red[5] + red[7];
  float mu = sum * (1.0f / DM);
  float var = sq * (1.0f / DM) - mu * mu;
  float rstd = rsqrtf(var + 1e-5f);
  bf16x4 g4 = ((const bf16x4*)g)[tid];
  bf16x4 b4 = ((const bf16x4*)be)[tid];
  float y0 = (s0 - mu) * rstd * (float)g4[0] + (float)b4[0];
  float y1 = (s1 - mu) * rstd * (float)g4[1] + (float)b4[1];
  float y2 = (s2 - mu) * rstd * (float)g4[2] + (float)b4[2];
  float y3 = (s3 - mu) * rstd * (float)g4[3] + (float)b4[3];
  if (yb) {
    bf16x4 ob = {(bf16)y0, (bf16)y1, (bf16)y2, (bf16)y3};
    ((bf16x4*)(yb + (size_t)row * DM))[tid] = ob;
  }
  if (outAny) {
    if (*flag) {
      bf16x4 ob = {(bf16)y0, (bf16)y1, (bf16)y2, (bf16)y3};
      ((bf16x4*)outAny)[(size_t)row * 256 + tid] = ob;
    } else {
      ((float4*)outAny)[(size_t)row * 256 + tid] = make_float4(y0, y1, y2, y3);
    }
  }
}

extern "C" void kernel_launch(void* const* d_in, const int* in_sizes, int n_in,
                              void* d_out, int out_size, void* d_ws, size_t ws_size,
                              hipStream_t stream) {
  (void)in_sizes; (void)n_in; (void)out_size; (void)ws_size;
  const void* x_raw   = d_in[0];
  const void* enc_raw = d_in[1];

  char* ws = (char*)d_ws;
  size_t off = 0;
  auto alloc = [&](size_t bytes) -> void* {
    void* p = ws + off;
    off += (bytes + 255) & ~(size_t)255;
    return p;
  };
  const size_t SB = (size_t)MR * DM;
  int* flag    = (int*)alloc(256);
  bf16* smallb = (bf16*)alloc(20480 * 2);
  bf16* wt   = (bf16*)alloc((size_t)16 * MEG * 2);
  bf16* xb   = (bf16*)alloc(SB * 2);
  bf16* encb = (bf16*)alloc(SB * 2);
  bf16* vtg  = (bf16*)alloc(SB * 2);
  bf16* ctx  = (bf16*)alloc(SB * 2);
  bf16* hb1  = (bf16*)alloc(SB * 2);
  bf16* hb2  = (bf16*)alloc(SB * 2);
  bf16* qkv  = (bf16*)alloc(SB * 3 * 2);
  bf16* kvc  = (bf16*)alloc(SB * 2 * 2);
  float* part = (float*)alloc(SB * 5 * 4);  // 5 slices (flash nsplit=5)
  float* lpart = (float*)alloc((size_t)5 * BB * NH * SEQ * 4);
  bf16* gbuf = qkv;
  bf16* qc   = xb;

  bf16* b_qkvs = smallb + 0;     bf16* b_os  = smallb + 3072;
  bf16* b_qc   = smallb + 4096;  bf16* b_kvc = smallb + 5120;
  bf16* b_oc   = smallb + 7168;  bf16* b_f1  = smallb + 8192;
  bf16* b_f2   = smallb + 12288;
  bf16* l1g = smallb + 13312; bf16* l1b = smallb + 14336;
  bf16* l2g = smallb + 15360; bf16* l2b = smallb + 16384;
  bf16* l3g = smallb + 17408; bf16* l3b = smallb + 18432;

  detect_kernel<<<1, 64, 0, stream>>>((const unsigned int*)x_raw, flag);
  cvt_big2_kernel<<<dim3((int)(SB / 1024), 2), 256, 0, stream>>>(
      x_raw, xb, enc_raw, encb, (int)(SB / 4), flag);
  P16 ps;
  ps.p[0] = d_in[5];  ps.p[1] = d_in[7];  ps.p[2] = d_in[9];  ps.p[3] = d_in[11];
  ps.p[4] = d_in[13]; ps.p[5] = d_in[15]; ps.p[6] = d_in[17]; ps.p[7] = d_in[19];
  ps.p[8] = d_in[21]; ps.p[9] = d_in[23];
  ps.p[10] = d_in[24]; ps.p[11] = d_in[25]; ps.p[12] = d_in[26];
  ps.p[13] = d_in[27]; ps.p[14] = d_in[28]; ps.p[15] = d_in[29];
  cvt_small_kernel<<<16, 256, 0, stream>>>(ps, smallb, flag);

  WTB wb;
  const int wsrc[10] = {4, 6, 8, 10, 12, 14, 16, 18, 20, 22};
  for (int i = 0; i < 10; ++i) {
    wb.src[i] = d_in[wsrc[i]];
    wb.K[i] = 1024; wb.N[i] = 1024;
    wb.dstoff[i] = i * MEG;
  }
  wb.N[8] = 4096;
  wb.K[9] = 4096; wb.dstoff[9] = 12 * MEG;
  int bacc = 0;
  for (int i = 0; i < 10; ++i) {
    wb.bstart[i] = bacc;
    bacc += (wb.N[i] / 64) * (wb.K[i] / 32);
  }
  wt_all_kernel<<<bacc, 256, 0, stream>>>(wb, wt, flag);

  // ---- self attention (causal, kv-split x5: grid 2560 = 2 x 5 blocks/CU) --
  gemm_kernel<128><<<24 * 32, 256, 0, stream>>>(xb, wt, b_qkvs, qkv,
                                                MR, 3072, DM, 0, 24);
  vt_pre_kernel<<<dim3(SEQ / 32, 2, 32), 256, 0, stream>>>(qkv + 2048, 3072, vtg, SEQ);
  flash9_kernel<<<16 * 16 * BB * 5, 256, 0, stream>>>(
      qkv, 3072, qkv + 1024, 3072, vtg, ctx, part, lpart, SEQ, 1, 5);
  flash_comb_kernel<5><<<MR, 256, 0, stream>>>(part, lpart, ctx);
  gemm_splitk_kernel<<<8 * 32 * 2, 256, 0, stream>>>(
      ctx, wt + (size_t)3 * MEG, part, MR, DM, 512, DM, 8);
  addnorm_red_kernel<2><<<MR, 256, 0, stream>>>(xb, part, b_os, l1g, l1b,
                                                hb1, nullptr, flag);
  // ---- cross attention (kv-split x5) ----
  gemm_kernel<64><<<8 * 64, 256, 0, stream>>>(hb1, wt + (size_t)4 * MEG,
                                              b_qc, qc, MR, DM, DM, 0, 8);
  gemm_kernel<128><<<16 * 32, 256, 0, stream>>>(encb, wt + (size_t)5 * MEG,
                                                b_kvc, kvc, MR, 2048, DM, 0, 16);
  vt_pre_kernel<<<dim3(SEQ / 32, 2, 32), 256, 0, stream>>>(kvc + 1024, 2048, vtg, SEQ);
  flash9_kernel<<<16 * 16 * BB * 5, 256, 0, stream>>>(
      qc, 1024, kvc, 2048, vtg, ctx, part, lpart, SEQ, 0, 5);
  flash_comb_kernel<5><<<MR, 256, 0, stream>>>(part, lpart, ctx);
  gemm_splitk_kernel<<<8 * 32 * 2, 256, 0, stream>>>(
      ctx, wt + (size_t)7 * MEG, part, MR, DM, 512, DM, 8);
  addnorm_red_kernel<2><<<MR, 256, 0, stream>>>(hb1, part, b_oc, l2g, l2b,
                                                hb2, nullptr, flag);
  // ---- FFN ----
  gemm_kernel<128><<<32 * 32, 256, 0, stream>>>(hb2, wt + (size_t)8 * MEG,
                                                b_f1, gbuf, MR, DFF, DM, 1, 32);
  gemm_splitk_kernel<<<8 * 32 * 4, 256, 0, stream>>>(
      gbuf, wt + (size_t)12 * MEG, part, MR, DM, 1024, DFF, 8);
  addnorm_red_kernel<4><<<MR, 256, 0, stream>>>(hb2, part, b_f2, l3g, l3b,
                                                nullptr, d_out, flag);
}

// Round 11
// 622.701 us; speedup vs baseline: 1.7997x; 1.0181x over previous
//
#include <hip/hip_runtime.h>
#include <stdint.h>

typedef __bf16 bf16;
typedef __attribute__((ext_vector_type(4))) float f32x4;
typedef __attribute__((ext_vector_type(8))) __bf16 bf16x8;
typedef __attribute__((ext_vector_type(4))) __bf16 bf16x4;
typedef __attribute__((ext_vector_type(4))) short s16x4;

#define DM   1024
#define NH   16
#define HDIM 64
#define BB   2
#define SEQ  2048
#define MR   (BB * SEQ)
#define DFF  4096
#define MEG  (1024 * 1024)

// ---------------- dtype detection: 1 = bf16, 0 = f32 ----------------
__global__ void detect_kernel(const unsigned int* __restrict__ xw,
                              int* __restrict__ flag) {
  int tid = threadIdx.x;
  int bad = 0;
  for (int i = tid; i < 4096; i += 64) {
    unsigned int w = xw[i];
    float flo = __uint_as_float((w & 0xffffu) << 16);
    if (!(fabsf(flo) < 100.f)) bad = 1;
  }
  unsigned long long m = __ballot(bad);
  if (tid == 0) *flag = (m == 0ull) ? 1 : 0;
}

// ---------------- input canonicalization -> bf16 (both tensors, 1 launch) --
__global__ __launch_bounds__(256) void cvt_big2_kernel(
    const void* __restrict__ src0, bf16* __restrict__ dst0,
    const void* __restrict__ src1, bf16* __restrict__ dst1,
    int n4, const int* __restrict__ flag) {
  int i = blockIdx.x * 256 + threadIdx.x;
  if (i >= n4) return;
  const void* src = blockIdx.y ? src1 : src0;
  bf16* dst = blockIdx.y ? dst1 : dst0;
  if (*flag) {
    ((bf16x4*)dst)[i] = ((const bf16x4*)src)[i];
  } else {
    float4 v = ((const float4*)src)[i];
    bf16x4 o = {(bf16)v.x, (bf16)v.y, (bf16)v.z, (bf16)v.w};
    ((bf16x4*)dst)[i] = o;
  }
}

struct P16 { const void* p[16]; };
__global__ __launch_bounds__(256) void cvt_small_kernel(
    P16 ps, bf16* __restrict__ dstbase, const int* __restrict__ flag) {
  const int ncnt[16] = {1024,1024,1024,1024,1024,1024,1024,1024,
                        4096,1024,1024,1024,1024,1024,1024,1024};
  const int doff[16] = {0,1024,2048,3072,4096,5120,6144,7168,
                        8192,12288,13312,14336,15360,16384,17408,18432};
  int b = blockIdx.x;
  int n = ncnt[b];
  bool isbf = (*flag) != 0;
  const void* s = ps.p[b];
  bf16* d = dstbase + doff[b];
  for (int i = threadIdx.x; i * 4 < n; i += 256) {
    if (isbf) {
      ((bf16x4*)d)[i] = ((const bf16x4*)s)[i];
    } else {
      float4 v = ((const float4*)s)[i];
      bf16x4 o = {(bf16)v.x, (bf16)v.y, (bf16)v.z, (bf16)v.w};
      ((bf16x4*)d)[i] = o;
    }
  }
}

// ---------------- async global->LDS, 16B per lane ----------------
static __device__ __forceinline__ void gl_lds16(const bf16* g, bf16* l) {
  auto gp = reinterpret_cast<__attribute__((address_space(1))) unsigned int*>(
      reinterpret_cast<uintptr_t>(g));
  auto lp = reinterpret_cast<__attribute__((address_space(3))) unsigned int*>(
      (unsigned int)reinterpret_cast<uintptr_t>(l));
  __builtin_amdgcn_global_load_lds(gp, lp, 16, 0, 0);
}

static __device__ __forceinline__ s16x4 as_s16x4(bf16x4 v) {
  s16x4 r;
  __builtin_memcpy(&r, &v, 8);
  return r;
}

// ---------------- batched weight transpose v2: 64x32 tiles, u32 loads,
// b128 stores. wt[n][k] = w[k][n]. ----------------------------------------
struct WTB {
  const void* src[10];
  int dstoff[10];
  int K[10], N[10];
  int bstart[10];
};
__global__ __launch_bounds__(256) void wt_all_kernel(WTB wb, bf16* __restrict__ wtbase,
                                                     const int* __restrict__ flag) {
  __shared__ alignas(16) bf16 tile[64][40];  // 80B rows: 16B-aligned
  int bid = blockIdx.x;
  int wi = 0;
  while (wi < 9 && bid >= wb.bstart[wi + 1]) ++wi;
  int rel = bid - wb.bstart[wi];
  int N = wb.N[wi], K = wb.K[wi];
  int nb = N >> 6;
  int n0 = (rel % nb) * 64, k0 = (rel / nb) * 32;
  const void* w = wb.src[wi];
  bf16* wt = wtbase + wb.dstoff[wi];
  bool isbf = (*flag) != 0;
  int tid = threadIdx.x;
  int np = tid & 31, tk = tid >> 5;  // np: n-pair 0..31, tk: k-row base 0..7
#pragma unroll
  for (int i = 0; i < 4; ++i) {
    int kl = tk + i * 8;
    bf16 b0, b1;
    if (isbf) {
      unsigned int u = *(const unsigned int*)(
          (const bf16*)w + (size_t)(k0 + kl) * N + n0 + np * 2);
      unsigned short s0 = (unsigned short)(u & 0xffffu);
      unsigned short s1 = (unsigned short)(u >> 16);
      __builtin_memcpy(&b0, &s0, 2);
      __builtin_memcpy(&b1, &s1, 2);
    } else {
      const float* fp = (const float*)w + (size_t)(k0 + kl) * N + n0 + np * 2;
      b0 = (bf16)fp[0];
      b1 = (bf16)fp[1];
    }
    tile[np * 2][kl] = b0;
    tile[np * 2 + 1][kl] = b1;
  }
  __syncthreads();
  int nl = tid >> 2, kq = tid & 3;  // nl 0..63, kq*8: k-octet
  bf16x8 v = *(const bf16x8*)(&tile[nl][kq * 8]);
  *(bf16x8*)(wt + (size_t)(n0 + nl) * K + k0 + kq * 8) = v;
}

// ---------------- GEMM v2: BK=64 (2 sub-steps per barrier pair -> half the
// vmcnt(0)-drain stalls), flat grid + XCD swizzle, C = A @ Bt^T + bias -----
template <int TM>
__global__ __launch_bounds__(256) void gemm_kernel(
    const bf16* __restrict__ A, const bf16* __restrict__ Bt,
    const bf16* __restrict__ bias, bf16* __restrict__ outb,
    int M, int N, int K, int relu, int nbx) {
  constexpr int NI = TM / 32;
  constexpr int WM = TM / 2;
  constexpr int CA = TM / 64;
  __shared__ alignas(16) bf16 As[2][TM * 32];
  __shared__ alignas(16) bf16 Bs[2][128 * 32];
  int tid = threadIdx.x;
  int lane = tid & 63, wv = tid >> 6;
  int quad = lane >> 4, l15 = lane & 15;
  int wg = blockIdx.x;
  int w = (wg & 7) * (gridDim.x >> 3) + (wg >> 3);  // XCD-contiguous
  int bx = w % nbx, by = w / nbx;
  int m0 = by * TM, n0 = bx * 128;
  int wm = wv >> 1, wn = wv & 1;

  f32x4 acc[NI][4];
#pragma unroll
  for (int i = 0; i < NI; ++i)
#pragma unroll
    for (int j = 0; j < 4; ++j) acc[i][j] = (f32x4){0.f, 0.f, 0.f, 0.f};

  int sr = lane >> 2, sc = (lane & 3) * 8;
  const bf16* gA[CA];
  bf16* lA0[CA];
  bf16* lA1[CA];
#pragma unroll
  for (int t = 0; t < CA; ++t) {
    int ch = wv * CA + t;
    gA[t] = A + (size_t)(m0 + ch * 16 + sr) * K + sc;
    lA0[t] = As[0] + ch * 512 + lane * 8;
    lA1[t] = As[1] + ch * 512 + lane * 8;
  }
  const bf16* gB0 = Bt + (size_t)(n0 + (wv * 2) * 16 + sr) * K + sc;
  const bf16* gB1 = Bt + (size_t)(n0 + (wv * 2 + 1) * 16 + sr) * K + sc;
  bf16* lB00 = Bs[0] + (wv * 2) * 512 + lane * 8;
  bf16* lB01 = Bs[1] + (wv * 2) * 512 + lane * 8;
  bf16* lB10 = Bs[0] + (wv * 2 + 1) * 512 + lane * 8;
  bf16* lB11 = Bs[1] + (wv * 2 + 1) * 512 + lane * 8;

  for (int k0 = 0; k0 < K; k0 += 64) {
#pragma unroll
    for (int t = 0; t < CA; ++t) {
      gl_lds16(gA[t] + k0, lA0[t]);
      gl_lds16(gA[t] + k0 + 32, lA1[t]);
    }
    gl_lds16(gB0 + k0, lB00);
    gl_lds16(gB0 + k0 + 32, lB01);
    gl_lds16(gB1 + k0, lB10);
    gl_lds16(gB1 + k0 + 32, lB11);
    __syncthreads();
#pragma unroll
    for (int s = 0; s < 2; ++s) {
      bf16x8 af[NI], bfr[4];
#pragma unroll
      for (int i = 0; i < NI; ++i)
        af[i] = *(const bf16x8*)(As[s] + (wm * WM + i * 16 + l15) * 32 + quad * 8);
#pragma unroll
      for (int j = 0; j < 4; ++j)
        bfr[j] = *(const bf16x8*)(Bs[s] + (wn * 64 + j * 16 + l15) * 32 + quad * 8);
#pragma unroll
      for (int i = 0; i < NI; ++i)
#pragma unroll
        for (int j = 0; j < 4; ++j)
          acc[i][j] = __builtin_amdgcn_mfma_f32_16x16x32_bf16(af[i], bfr[j],
                                                              acc[i][j], 0, 0, 0);
    }
    __syncthreads();
  }

#pragma unroll
  for (int j = 0; j < 4; ++j) {
    int col = n0 + wn * 64 + j * 16 + l15;
    float bval = (float)bias[col];
#pragma unroll
    for (int i = 0; i < NI; ++i) {
      int rb = m0 + wm * WM + i * 16 + quad * 4;
#pragma unroll
      for (int r = 0; r < 4; ++r) {
        float v = acc[i][j][r] + bval;
        if (relu) v = fmaxf(v, 0.f);
        outb[(size_t)(rb + r) * N + col] = (bf16)v;
      }
    }
  }
}

// ---------------- split-K GEMM v2: BK=64, flat grid + XCD swizzle --------
__global__ __launch_bounds__(256) void gemm_splitk_kernel(
    const bf16* __restrict__ A, const bf16* __restrict__ Bt,
    float* __restrict__ pout, int M, int N, int KC, int Ktot, int nbx) {
  __shared__ alignas(16) bf16 As[2][128 * 32];
  __shared__ alignas(16) bf16 Bs[2][128 * 32];
  int tid = threadIdx.x;
  int lane = tid & 63, wv = tid >> 6;
  int quad = lane >> 4, l15 = lane & 15;
  int wg = blockIdx.x;
  int w = (wg & 7) * (gridDim.x >> 3) + (wg >> 3);  // XCD-contiguous
  int nxy = nbx * (M >> 7);
  int bz = w / nxy;
  int rem = w - bz * nxy;
  int bx = rem % nbx, by = rem / nbx;
  int m0 = by * 128, n0 = bx * 128;
  int wm = wv >> 1, wn = wv & 1;
  int kb = bz * KC;
  pout += (size_t)bz * M * N;

  f32x4 acc[4][4];
#pragma unroll
  for (int i = 0; i < 4; ++i)
#pragma unroll
    for (int j = 0; j < 4; ++j) acc[i][j] = (f32x4){0.f, 0.f, 0.f, 0.f};

  int sr = lane >> 2, sc = (lane & 3) * 8;
  const bf16* gA0 = A + (size_t)(m0 + (wv * 2) * 16 + sr) * Ktot + sc;
  const bf16* gA1 = A + (size_t)(m0 + (wv * 2 + 1) * 16 + sr) * Ktot + sc;
  const bf16* gB0 = Bt + (size_t)(n0 + (wv * 2) * 16 + sr) * Ktot + sc;
  const bf16* gB1 = Bt + (size_t)(n0 + (wv * 2 + 1) * 16 + sr) * Ktot + sc;
  bf16* lA00 = As[0] + (wv * 2) * 512 + lane * 8;
  bf16* lA01 = As[1] + (wv * 2) * 512 + lane * 8;
  bf16* lA10 = As[0] + (wv * 2 + 1) * 512 + lane * 8;
  bf16* lA11 = As[1] + (wv * 2 + 1) * 512 + lane * 8;
  bf16* lB00 = Bs[0] + (wv * 2) * 512 + lane * 8;
  bf16* lB01 = Bs[1] + (wv * 2) * 512 + lane * 8;
  bf16* lB10 = Bs[0] + (wv * 2 + 1) * 512 + lane * 8;
  bf16* lB11 = Bs[1] + (wv * 2 + 1) * 512 + lane * 8;

  for (int k0 = kb; k0 < kb + KC; k0 += 64) {
    gl_lds16(gA0 + k0, lA00);
    gl_lds16(gA0 + k0 + 32, lA01);
    gl_lds16(gA1 + k0, lA10);
    gl_lds16(gA1 + k0 + 32, lA11);
    gl_lds16(gB0 + k0, lB00);
    gl_lds16(gB0 + k0 + 32, lB01);
    gl_lds16(gB1 + k0, lB10);
    gl_lds16(gB1 + k0 + 32, lB11);
    __syncthreads();
#pragma unroll
    for (int s = 0; s < 2; ++s) {
      bf16x8 af[4], bfr[4];
#pragma unroll
      for (int i = 0; i < 4; ++i)
        af[i] = *(const bf16x8*)(As[s] + (wm * 64 + i * 16 + l15) * 32 + quad * 8);
#pragma unroll
      for (int j = 0; j < 4; ++j)
        bfr[j] = *(const bf16x8*)(Bs[s] + (wn * 64 + j * 16 + l15) * 32 + quad * 8);
#pragma unroll
      for (int i = 0; i < 4; ++i)
#pragma unroll
        for (int j = 0; j < 4; ++j)
          acc[i][j] = __builtin_amdgcn_mfma_f32_16x16x32_bf16(af[i], bfr[j],
                                                              acc[i][j], 0, 0, 0);
    }
    __syncthreads();
  }
#pragma unroll
  for (int j = 0; j < 4; ++j) {
    int col = n0 + wn * 64 + j * 16 + l15;
#pragma unroll
    for (int i = 0; i < 4; ++i) {
      int rb = m0 + wm * 64 + i * 16 + quad * 4;
#pragma unroll
      for (int r = 0; r < 4; ++r)
        pout[(size_t)(rb + r) * N + col] = acc[i][j][r];
    }
  }
}

// ---------------- V pre-transpose: [b][kv][h*64+d] -> [b*NH+h][d][skv] ----
__global__ __launch_bounds__(256) void vt_pre_kernel(
    const bf16* __restrict__ v, int vstride, bf16* __restrict__ vt, int skv) {
  __shared__ bf16 tile[32][33];
  int tid = threadIdx.x;
  int tx = tid & 31, ty = tid >> 5;
  int kv0 = blockIdx.x * 32, d0 = blockIdx.y * 32;
  int bh = blockIdx.z;
  int b = bh >> 4, h = bh & 15;
  const bf16* src = v + (size_t)b * skv * vstride + h * HDIM;
#pragma unroll
  for (int i = 0; i < 4; ++i)
    tile[ty + i * 8][tx] = src[(size_t)(kv0 + ty + i * 8) * vstride + d0 + tx];
  __syncthreads();
  bf16* dst = vt + ((size_t)bh * HDIM + d0) * skv + kv0;
#pragma unroll
  for (int i = 0; i < 4; ++i)
    dst[(size_t)(ty + i * 8) * skv + tx] = tile[tx][ty + i * 8];
}

// ---------------- flash v9 (R7 known-good): no LDS P, XOR-swizzled K/V via
// global_load_lds, dbuf 32KB LDS, 1 barrier/chunk, XCD swizzle, nsplit=2 ---
__global__ __launch_bounds__(256, 4) void flash9_kernel(
    const bf16* __restrict__ Q, int qstride,
    const bf16* __restrict__ Kk, int kstride,
    const bf16* __restrict__ VT, bf16* __restrict__ ctx,
    float* __restrict__ opart, float* __restrict__ lpart,
    int skv, int causal, int nsplit) {
  __shared__ alignas(16) bf16 KTl[2][64 * 64];
  __shared__ alignas(16) bf16 VTl[2][64 * 64];
  int tid = threadIdx.x;
  int lane = tid & 63, wv = tid >> 6, quad = lane >> 4, l15 = lane & 15;
  int wg = blockIdx.x;
  int cpx = gridDim.x >> 3;
  int w = (wg & 7) * cpx + (wg >> 3);  // XCD-contiguous work id
  int qb = w & 15;
  int h = (w >> 4) & 15;
  int zz = w >> 8;
  int b = zz / nsplit;
  int half = zz - b * nsplit;
  int q0 = qb * 128;
  int qw = q0 + wv * 32;
  int l7 = l15 & 7;

  // Q as B-operand of QK^T; fold 0.125*log2(e) so softmax is pure v_exp
  bf16x8 qf[2][2];
  const float qsc = 0.125f * 1.44269504f;
#pragma unroll
  for (int a = 0; a < 2; ++a) {
    const bf16* qp = Q + (size_t)(b * SEQ + qw + a * 16 + l15) * qstride + h * HDIM;
    qf[a][0] = *(const bf16x8*)(qp + quad * 8);
    qf[a][1] = *(const bf16x8*)(qp + 32 + quad * 8);
#pragma unroll
    for (int j = 0; j < 8; ++j) {
      qf[a][0][j] = (bf16)((float)qf[a][0][j] * qsc);
      qf[a][1][j] = (bf16)((float)qf[a][1][j] * qsc);
    }
  }
  s16x4 onesA = {0x3F80, 0x3F80, 0x3F80, 0x3F80};  // bf16 1.0 x4

  // o^T accumulators: o[a][jt] rows = d-local (quad*4+r), col = q (l15)
  f32x4 o[2][4], oL[2];
#pragma unroll
  for (int a = 0; a < 2; ++a) {
    oL[a] = (f32x4){0.f, 0.f, 0.f, 0.f};
#pragma unroll
    for (int j = 0; j < 4; ++j) o[a][j] = (f32x4){0.f, 0.f, 0.f, 0.f};
  }

  int nch_tot = causal ? (q0 + 128) / 64 : skv / 64;
  int c_lo = (half * nch_tot) / nsplit;
  int c_hi = ((half + 1) * nch_tot) / nsplit;

  // staging geometry: wave wv owns tile rows [wv*16, wv*16+16), two 8-row
  // gl_lds ops each. Global source col-segment pre-swizzled so that the
  // LINEAR lds write lands data at physical slot (colseg ^ (row&7)).
  int l8 = lane >> 3;
  int colseg = (lane & 7) ^ l8;  // (row&7)==l8 for both ops (row0%8==0)
  int grow = wv * 16 + l8;
  const bf16* kbase = Kk + ((size_t)b * skv + grow) * kstride + h * HDIM + colseg * 8;
  const bf16* vbase = VT + ((size_t)(b * NH + h) * HDIM + grow) * skv + colseg * 8;
  bf16* kls = &KTl[0][wv * 1024];  // lane-uniform dest base (lane0 value)
  bf16* vls = &VTl[0][wv * 1024];

  auto STAGE = [&](int bb, int cc) {
    const bf16* ks = kbase + (size_t)(cc * 64) * kstride;
    const bf16* vs = vbase + cc * 64;
    bf16* kd = kls + bb * 4096;
    bf16* vd = vls + bb * 4096;
    gl_lds16(ks, kd);
    gl_lds16(ks + (size_t)8 * kstride, kd + 512);
    gl_lds16(vs, vd);
    gl_lds16(vs + (size_t)8 * skv, vd + 512);
  };

  if (c_lo < c_hi) STAGE(0, c_lo);

  for (int c = c_lo; c < c_hi; ++c) {
    int cur = (c - c_lo) & 1;
    int kv0 = c * 64;
    __syncthreads();  // drains vmcnt -> buf[cur] staged; closes prev compute
    if (c + 1 < c_hi) STAGE(cur ^ 1, c + 1);  // in flight across this chunk

    if (!causal || kv0 <= qw + 31) {  // wave-uniform skip of masked chunks
      const bf16* kt_base = &KTl[0][0] + cur * 4096;
      const bf16* vt_base = &VTl[0][0] + cur * 4096;
      bf16x4 p[2][4];
      // S^T = K @ Q^T per 16-row kv tile t; convert to bf16 in-register
#pragma unroll
      for (int t = 0; t < 4; ++t) {
        const bf16* kb = kt_base + (t * 16 + l15) * 64;
        bf16x8 kt0 = *(const bf16x8*)(kb + ((quad ^ l7) << 3));
        bf16x8 kt1 = *(const bf16x8*)(kb + (((quad + 4) ^ l7) << 3));
#pragma unroll
        for (int a = 0; a < 2; ++a) {
          f32x4 z = (f32x4){0.f, 0.f, 0.f, 0.f};
          z = __builtin_amdgcn_mfma_f32_16x16x32_bf16(kt0, qf[a][0], z, 0, 0, 0);
          z = __builtin_amdgcn_mfma_f32_16x16x32_bf16(kt1, qf[a][1], z, 0, 0, 0);
          if (causal && kv0 + 63 > qw) {  // diagonal region: element mask
#pragma unroll
            for (int r = 0; r < 4; ++r)
              if (kv0 + t * 16 + quad * 4 + r > qw + a * 16 + l15)
                z[r] = -1e30f;
          }
          bf16x4 pk;
#pragma unroll
          for (int r = 0; r < 4; ++r) pk[r] = (bf16)exp2f(z[r]);
          p[a][t] = pk;
          // row-sum via ones-A MFMA: every lane gets l[q=l15] in all rows
          oL[a] = __builtin_amdgcn_mfma_f32_16x16x16bf16_1k(
              onesA, as_s16x4(pk), oL[a], 0, 0, 0);
        }
      }
      // PV: o^T[d][q] += V^T-frag (A) x P^T-D-frag (B), 16x16x16
#pragma unroll
      for (int jt = 0; jt < 4; ++jt) {
        const bf16* vb = vt_base + (jt * 16 + l15) * 64;
        bf16x4 af[4];
#pragma unroll
        for (int t = 0; t < 4; ++t)
          af[t] = *(const bf16x4*)(
              vb + ((((t * 2 + (quad >> 1)) ^ l7) << 3) + ((quad & 1) << 2)));
#pragma unroll
        for (int a = 0; a < 2; ++a)
#pragma unroll
          for (int t = 0; t < 4; ++t)
            o[a][jt] = __builtin_amdgcn_mfma_f32_16x16x16bf16_1k(
                as_s16x4(af[t]), as_s16x4(p[a][t]), o[a][jt], 0, 0, 0);
      }
    }
  }

  if (nsplit == 1) {
#pragma unroll
    for (int a = 0; a < 2; ++a) {
      float inv = 1.0f / fmaxf(oL[a][0], 1e-30f);
      bf16* cp = ctx + (size_t)(b * SEQ + qw + a * 16 + l15) * DM + h * HDIM + quad * 4;
#pragma unroll
      for (int jt = 0; jt < 4; ++jt) {
        bf16x4 ob = {(bf16)(o[a][jt][0] * inv), (bf16)(o[a][jt][1] * inv),
                     (bf16)(o[a][jt][2] * inv), (bf16)(o[a][jt][3] * inv)};
        *(bf16x4*)(cp + jt * 16) = ob;
      }
    }
  } else {
    // additive partials: fixed-shift softmax means o/l just sum across splits
#pragma unroll
    for (int a = 0; a < 2; ++a) {
      float* op = opart + (size_t)half * MR * DM +
                  (size_t)(b * SEQ + qw + a * 16 + l15) * DM + h * HDIM + quad * 4;
#pragma unroll
      for (int jt = 0; jt < 4; ++jt) *(f32x4*)(op + jt * 16) = o[a][jt];
      if (lane < 16)
        lpart[(size_t)((half * BB + b) * NH + h) * SEQ + qw + a * 16 + l15] =
            oL[a][0];
    }
  }
}

// ---------------- kv-split combine: ctx = sum(o_s) / sum(l_s) -------------
template <int NS>
__global__ __launch_bounds__(256) void flash_comb_kernel(
    const float* __restrict__ opart, const float* __restrict__ lpart,
    bf16* __restrict__ ctx) {
  int row = blockIdx.x, tid = threadIdx.x;
  int b = row >> 11, q = row & (SEQ - 1);
  int h = tid >> 4;
  float l = 0.f;
#pragma unroll
  for (int s = 0; s < NS; ++s)
    l += lpart[(size_t)((s * BB + b) * NH + h) * SEQ + q];
  float inv = 1.0f / fmaxf(l, 1e-30f);
  float a0 = 0.f, a1 = 0.f, a2 = 0.f, a3 = 0.f;
#pragma unroll
  for (int s = 0; s < NS; ++s) {
    f32x4 v = ((const f32x4*)(opart + (size_t)s * MR * DM + (size_t)row * DM))[tid];
    a0 += v[0]; a1 += v[1]; a2 += v[2]; a3 += v[3];
  }
  bf16x4 ob = {(bf16)(a0 * inv), (bf16)(a1 * inv),
               (bf16)(a2 * inv), (bf16)(a3 * inv)};
  ((bf16x4*)(ctx + (size_t)row * DM))[tid] = ob;
}

// ---------------- fused split-K reduce + bias + residual + LayerNorm ------
template <int NP>
__global__ __launch_bounds__(256) void addnorm_red_kernel(
    const bf16* __restrict__ res, const float* __restrict__ part,
    const bf16* __restrict__ bias, const bf16* __restrict__ g,
    const bf16* __restrict__ be, bf16* __restrict__ yb,
    void* __restrict__ outAny, const int* __restrict__ flag) {
  int row = blockIdx.x, tid = threadIdx.x;
  float a0 = 0.f, a1 = 0.f, a2 = 0.f, a3 = 0.f;
#pragma unroll
  for (int p = 0; p < NP; ++p) {
    float4 v = ((const float4*)(part + (size_t)p * MR * DM + (size_t)row * DM))[tid];
    a0 += v.x; a1 += v.y; a2 += v.z; a3 += v.w;
  }
  bf16x4 bb = ((const bf16x4*)bias)[tid];
  bf16x4 rr = ((const bf16x4*)(res + (size_t)row * DM))[tid];
  float s0 = (float)rr[0] + a0 + (float)bb[0];
  float s1 = (float)rr[1] + a1 + (float)bb[1];
  float s2 = (float)rr[2] + a2 + (float)bb[2];
  float s3 = (float)rr[3] + a3 + (float)bb[3];
  float sum = s0 + s1 + s2 + s3;
  float sq = s0 * s0 + s1 * s1 + s2 * s2 + s3 * s3;
#pragma unroll
  for (int mk = 32; mk >= 1; mk >>= 1) {
    sum += __shfl_xor(sum, mk, 64);
    sq += __shfl_xor(sq, mk, 64);
  }
  __shared__ float red[8];
  int wvi = tid >> 6, lane = tid & 63;
  if (lane == 0) { red[wvi * 2] = sum; red[wvi * 2 + 1] = sq; }
  __syncthreads();
  sum = red[0] + red[2] + red[4] + red[6];
  sq = red[1] + red[3] + red[5] + red[7];
  float mu = sum * (1.0f / DM);
  float var = sq * (1.0f / DM) - mu * mu;
  float rstd = rsqrtf(var + 1e-5f);
  bf16x4 g4 = ((const bf16x4*)g)[tid];
  bf16x4 b4 = ((const bf16x4*)be)[tid];
  float y0 = (s0 - mu) * rstd * (float)g4[0] + (float)b4[0];
  float y1 = (s1 - mu) * rstd * (float)g4[1] + (float)b4[1];
  float y2 = (s2 - mu) * rstd * (float)g4[2] + (float)b4[2];
  float y3 = (s3 - mu) * rstd * (float)g4[3] + (float)b4[3];
  if (yb) {
    bf16x4 ob = {(bf16)y0, (bf16)y1, (bf16)y2, (bf16)y3};
    ((bf16x4*)(yb + (size_t)row * DM))[tid] = ob;
  }
  if (outAny) {
    if (*flag) {
      bf16x4 ob = {(bf16)y0, (bf16)y1, (bf16)y2, (bf16)y3};
      ((bf16x4*)outAny)[(size_t)row * 256 + tid] = ob;
    } else {
      ((float4*)outAny)[(size_t)row * 256 + tid] = make_float4(y0, y1, y2, y3);
    }
  }
}

// ---------------- addnorm over bf16 y (bias already applied in GEMM) ------
__global__ __launch_bounds__(256) void addnorm_y_kernel(
    const bf16* __restrict__ res, const bf16* __restrict__ y,
    const bf16* __restrict__ g, const bf16* __restrict__ be,
    bf16* __restrict__ yb) {
  int row = blockIdx.x, tid = threadIdx.x;
  bf16x4 rr = ((const bf16x4*)(res + (size_t)row * DM))[tid];
  bf16x4 yy = ((const bf16x4*)(y + (size_t)row * DM))[tid];
  float s0 = (float)rr[0] + (float)yy[0];
  float s1 = (float)rr[1] + (float)yy[1];
  float s2 = (float)rr[2] + (float)yy[2];
  float s3 = (float)rr[3] + (float)yy[3];
  float sum = s0 + s1 + s2 + s3;
  float sq = s0 * s0 + s1 * s1 + s2 * s2 + s3 * s3;
#pragma unroll
  for (int mk = 32; mk >= 1; mk >>= 1) {
    sum += __shfl_xor(sum, mk, 64);
    sq += __shfl_xor(sq, mk, 64);
  }
  __shared__ float red[8];
  int wvi = tid >> 6, lane = tid & 63;
  if (lane == 0) { red[wvi * 2] = sum; red[wvi * 2 + 1] = sq; }
  __syncthreads();
  sum = red[0] + red[2] + red[4] + red[6];
  sq = red[1] + red[3] + red[5] + red[7];
  float mu = sum * (1.0f / DM);
  float var = sq * (1.0f / DM) - mu * mu;
  float rstd = rsqrtf(var + 1e-5f);
  bf16x4 g4 = ((const bf16x4*)g)[tid];
  bf16x4 b4 = ((const bf16x4*)be)[tid];
  bf16x4 ob = {(bf16)((s0 - mu) * rstd * (float)g4[0] + (float)b4[0]),
               (bf16)((s1 - mu) * rstd * (float)g4[1] + (float)b4[1]),
               (bf16)((s2 - mu) * rstd * (float)g4[2] + (float)b4[2]),
               (bf16)((s3 - mu) * rstd * (float)g4[3] + (float)b4[3])};
  ((bf16x4*)(yb + (size_t)row * DM))[tid] = ob;
}

extern "C" void kernel_launch(void* const* d_in, const int* in_sizes, int n_in,
                              void* d_out, int out_size, void* d_ws, size_t ws_size,
                              hipStream_t stream) {
  (void)in_sizes; (void)n_in; (void)out_size; (void)ws_size;
  const void* x_raw   = d_in[0];
  const void* enc_raw = d_in[1];

  char* ws = (char*)d_ws;
  size_t off = 0;
  auto alloc = [&](size_t bytes) -> void* {
    void* p = ws + off;
    off += (bytes + 255) & ~(size_t)255;
    return p;
  };
  const size_t SB = (size_t)MR * DM;
  int* flag    = (int*)alloc(256);
  bf16* smallb = (bf16*)alloc(20480 * 2);
  bf16* wt   = (bf16*)alloc((size_t)16 * MEG * 2);
  bf16* xb   = (bf16*)alloc(SB * 2);
  bf16* encb = (bf16*)alloc(SB * 2);
  bf16* vtg  = (bf16*)alloc(SB * 2);
  bf16* ctx  = (bf16*)alloc(SB * 2);
  bf16* hb1  = (bf16*)alloc(SB * 2);
  bf16* hb2  = (bf16*)alloc(SB * 2);
  bf16* qkv  = (bf16*)alloc(SB * 3 * 2);
  bf16* kvc  = (bf16*)alloc(SB * 2 * 2);
  float* part = (float*)alloc(SB * 4 * 4);
  float* lpart = (float*)alloc((size_t)2 * BB * NH * SEQ * 4);
  bf16* gbuf = qkv;
  bf16* qc   = xb;
  bf16* yo   = (bf16*)part;  // O-proj direct output (part is free then)

  bf16* b_qkvs = smallb + 0;     bf16* b_os  = smallb + 3072;
  bf16* b_qc   = smallb + 4096;  bf16* b_kvc = smallb + 5120;
  bf16* b_oc   = smallb + 7168;  bf16* b_f1  = smallb + 8192;
  bf16* b_f2   = smallb + 12288;
  bf16* l1g = smallb + 13312; bf16* l1b = smallb + 14336;
  bf16* l2g = smallb + 15360; bf16* l2b = smallb + 16384;
  bf16* l3g = smallb + 17408; bf16* l3b = smallb + 18432;

  detect_kernel<<<1, 64, 0, stream>>>((const unsigned int*)x_raw, flag);
  cvt_big2_kernel<<<dim3((int)(SB / 1024), 2), 256, 0, stream>>>(
      x_raw, xb, enc_raw, encb, (int)(SB / 4), flag);
  P16 ps;
  ps.p[0] = d_in[5];  ps.p[1] = d_in[7];  ps.p[2] = d_in[9];  ps.p[3] = d_in[11];
  ps.p[4] = d_in[13]; ps.p[5] = d_in[15]; ps.p[6] = d_in[17]; ps.p[7] = d_in[19];
  ps.p[8] = d_in[21]; ps.p[9] = d_in[23];
  ps.p[10] = d_in[24]; ps.p[11] = d_in[25]; ps.p[12] = d_in[26];
  ps.p[13] = d_in[27]; ps.p[14] = d_in[28]; ps.p[15] = d_in[29];
  cvt_small_kernel<<<16, 256, 0, stream>>>(ps, smallb, flag);

  WTB wb;
  const int wsrc[10] = {4, 6, 8, 10, 12, 14, 16, 18, 20, 22};
  for (int i = 0; i < 10; ++i) {
    wb.src[i] = d_in[wsrc[i]];
    wb.K[i] = 1024; wb.N[i] = 1024;
    wb.dstoff[i] = i * MEG;
  }
  wb.N[8] = 4096;
  wb.K[9] = 4096; wb.dstoff[9] = 12 * MEG;
  int bacc = 0;
  for (int i = 0; i < 10; ++i) {
    wb.bstart[i] = bacc;
    bacc += (wb.N[i] / 64) * (wb.K[i] / 32);
  }
  wt_all_kernel<<<bacc, 256, 0, stream>>>(wb, wt, flag);

  // ---- self attention (causal, kv-split x2 + additive combine) ----
  gemm_kernel<128><<<24 * 32, 256, 0, stream>>>(xb, wt, b_qkvs, qkv,
                                                MR, 3072, DM, 0, 24);
  vt_pre_kernel<<<dim3(SEQ / 32, 2, 32), 256, 0, stream>>>(qkv + 2048, 3072, vtg, SEQ);
  flash9_kernel<<<16 * 16 * BB * 2, 256, 0, stream>>>(
      qkv, 3072, qkv + 1024, 3072, vtg, ctx, part, lpart, SEQ, 1, 2);
  flash_comb_kernel<2><<<MR, 256, 0, stream>>>(part, lpart, ctx);
  // O-proj direct (same 512-block occupancy as splitk, zero partial traffic)
  gemm_kernel<64><<<8 * 64, 256, 0, stream>>>(ctx, wt + (size_t)3 * MEG,
                                              b_os, yo, MR, DM, DM, 0, 8);
  addnorm_y_kernel<<<MR, 256, 0, stream>>>(xb, yo, l1g, l1b, hb1);
  // ---- cross attention (kv-split x2 + additive combine) ----
  gemm_kernel<64><<<8 * 64, 256, 0, stream>>>(hb1, wt + (size_t)4 * MEG,
                                              b_qc, qc, MR, DM, DM, 0, 8);
  gemm_kernel<128><<<16 * 32, 256, 0, stream>>>(encb, wt + (size_t)5 * MEG,
                                                b_kvc, kvc, MR, 2048, DM, 0, 16);
  vt_pre_kernel<<<dim3(SEQ / 32, 2, 32), 256, 0, stream>>>(kvc + 1024, 2048, vtg, SEQ);
  flash9_kernel<<<16 * 16 * BB * 2, 256, 0, stream>>>(
      qc, 1024, kvc, 2048, vtg, ctx, part, lpart, SEQ, 0, 2);
  flash_comb_kernel<2><<<MR, 256, 0, stream>>>(part, lpart, ctx);
  gemm_kernel<64><<<8 * 64, 256, 0, stream>>>(ctx, wt + (size_t)7 * MEG,
                                              b_oc, yo, MR, DM, DM, 0, 8);
  addnorm_y_kernel<<<MR, 256, 0, stream>>>(hb1, yo, l2g, l2b, hb2);
  // ---- FFN ----
  gemm_kernel<128><<<32 * 32, 256, 0, stream>>>(hb2, wt + (size_t)8 * MEG,
                                                b_f1, gbuf, MR, DFF, DM, 1, 32);
  gemm_splitk_kernel<<<8 * 32 * 4, 256, 0, stream>>>(
      gbuf, wt + (size_t)12 * MEG, part, MR, DM, 1024, DFF, 8);
  addnorm_red_kernel<4><<<MR, 256, 0, stream>>>(hb2, part, b_f2, l3g, l3b,
                                                nullptr, d_out, flag);
}